// Round 10
// baseline (4517.267 us; speedup 1.0000x reference)
//
#include <hip/hip_runtime.h>

#define N_RAYS 16384

typedef float v2f __attribute__((ext_vector_type(2)));
typedef float v4f __attribute__((ext_vector_type(4)));

// LDS weight layout (float offsets) — small weights only; W2 stays in global (L1-hot)
#define W1I   0        // [64][4] : {w1x, w1y, w1z, b1}
#define B2    256      // [64]
#define W3    320      // [64]
#define WTOT  384

// wave-local "barrier": compiler ordering only; HW DS pipe is in-order per wave
#define WSYNC() do { __builtin_amdgcn_wave_barrier(); asm volatile("" ::: "memory"); } while (0)

__device__ __forceinline__ float softplusf_(float x) {
    float e = __builtin_amdgcn_exp2f(fabsf(x) * -1.44269504088896340736f);
    float l = __builtin_amdgcn_logf(1.f + e);   // log2(1+e)
    return fmaxf(x, 0.f) + 0.69314718055994530942f * l;
}

__device__ __forceinline__ float sigmoidf_(float x) {
    float e = __builtin_amdgcn_exp2f(-fabsf(x) * 1.44269504088896340736f);
    float r = __builtin_amdgcn_rcpf(1.f + e);
    return x >= 0.f ? r : e * r;
}

__device__ __forceinline__ float frcp_(float x) { return __builtin_amdgcn_rcpf(x); }

__device__ __forceinline__ float scan_mul64(float x, int lane) {
#pragma unroll
    for (int d = 1; d < 64; d <<= 1) {
        float y = __shfl_up(x, d, 64);
        if (lane >= d) x *= y;
    }
    return x;
}

__device__ __forceinline__ float scan_add64(float x, int lane) {
#pragma unroll
    for (int d = 1; d < 64; d <<= 1) {
        float y = __shfl_up(x, d, 64);
        if (lane >= d) x += y;
    }
    return x;
}

__global__ __launch_bounds__(256, 4) void neus_render_kernel(
    const float* __restrict__ rays_o, const float* __restrict__ rays_d,
    const float* __restrict__ nearp, const float* __restrict__ farp,
    const float* __restrict__ sptr,
    const float* __restrict__ sw1, const float* __restrict__ sb1,
    const float* __restrict__ sw2, const float* __restrict__ sb2,
    const float* __restrict__ sw3, const float* __restrict__ sb3,
    const float* __restrict__ rw1, const float* __restrict__ rb1,
    const float* __restrict__ rw2, const float* __restrict__ rb2,
    float* __restrict__ outp) {
    const int tid = threadIdx.x;
    const int wave = tid >> 6;
    const int lane = tid & 63;
    const int ray = blockIdx.x * 4 + wave;

    __shared__ float wl[WTOT];
    __shared__ float dlds[4][132], slds[4][132];

    // ---- ray data loads (issue early) ----
    float ox = rays_o[ray * 3], oy = rays_o[ray * 3 + 1], oz = rays_o[ray * 3 + 2];
    float dxv = rays_d[ray * 3], dyv = rays_d[ray * 3 + 1], dzv = rays_d[ray * 3 + 2];
    const float nearv = nearp[ray], farv = farp[ray];
    const float sb3v = sb3[0];
    const float sfin = sptr[0];
    const float rb2x = rb2[0], rb2y = rb2[1], rb2z = rb2[2];

    // ---- stage only the small weights in LDS; W2 reads stay global (L1-hot) ----
    if (tid < 64) {
        int i = tid;
        wl[W1I + 4 * i + 0] = sw1[i];
        wl[W1I + 4 * i + 1] = sw1[64 + i];
        wl[W1I + 4 * i + 2] = sw1[128 + i];
        wl[W1I + 4 * i + 3] = sb1[i];
        wl[B2 + i] = sb2[i];
        wl[W3 + i] = sw3[i];
    }
    __syncthreads();

    float nrm = sqrtf(dxv * dxv + dyv * dyv + dzv * dzv);
    dxv /= nrm; dyv /= nrm; dzv /= nrm;

    float* dcur = &dlds[wave][0];
    float* scur = &slds[wave][0];

    // ---- coarse: 64 samples, one per lane ----
    {
        float t = (float)lane / 63.f;
        float dc = nearv * (1.f - t) + farv * t;
        float px = fmaf(dc, dxv, ox), py = fmaf(dc, dyv, oy), pz = fmaf(dc, dzv, oz);
        v2f acc[32];
        const v2f* b2v = (const v2f*)&wl[B2];
#pragma unroll
        for (int j = 0; j < 32; j++) acc[j] = b2v[j];
#pragma unroll 4
        for (int k = 0; k < 64; k++) {
            v4f wk = *(const v4f*)&wl[W1I + 4 * k];
            float a = wk.w;
            a = fmaf(px, wk.x, a);
            a = fmaf(py, wk.y, a);
            a = fmaf(pz, wk.z, a);
            float h = softplusf_(a);
            v2f hh = {h, h};
            const v4f* row4 = (const v4f*)(sw2 + (k << 6));   // global, wave-uniform
#pragma unroll
            for (int j4 = 0; j4 < 16; j4++) {
                v4f r = row4[j4];
                v2f rlo = {r.x, r.y}, rhi = {r.z, r.w};
                acc[2 * j4] = __builtin_elementwise_fma(hh, rlo, acc[2 * j4]);
                acc[2 * j4 + 1] = __builtin_elementwise_fma(hh, rhi, acc[2 * j4 + 1]);
            }
        }
        float out = sb3v;
#pragma unroll
        for (int j = 0; j < 32; j++) {
            out = fmaf(softplusf_(acc[j].x), wl[W3 + 2 * j], out);
            out = fmaf(softplusf_(acc[j].y), wl[W3 + 2 * j + 1], out);
        }
        dcur[lane] = dc;
        scur[lane] = sqrtf(px * px + py * py + pz * pz) - 0.8f + 0.1f * out;
    }
    WSYNC();

    int M = 64;
#pragma unroll 1
    for (int it = 0; it < 4; ++it) {
        const float s_it = 64.f * (float)(1 << it);
        const int nI = M - 1;

        // ---- dot_val + alpha, in registers (i0 = lane, i1 = 64+lane) ----
        float s_a0 = scur[lane], s_b0 = scur[lane + 1];
        float z_a0 = dcur[lane], z_b0 = dcur[lane + 1];
        float s_a1 = scur[64 + lane], s_b1 = scur[64 + lane + 1];
        float z_a1 = dcur[64 + lane], z_b1 = dcur[64 + lane + 1];
        float dv0 = (s_b0 - s_a0) * frcp_(z_b0 - z_a0 + 1e-5f);
        float dv1 = (s_b1 - s_a1) * frcp_(z_b1 - z_a1 + 1e-5f);
        float pdv0 = __shfl_up(dv0, 1, 64); if (lane == 0) pdv0 = 0.f;
        float t_p = __shfl_up(dv1, 1, 64);
        float t_63 = __shfl(dv0, 63, 64);
        float pdv1 = (lane == 0) ? t_63 : t_p;

        float a0, a1;
        {
            float dv = fminf(fmaxf(fminf(pdv0, dv0), -10.f), 0.f);
            float mid = (s_a0 + s_b0) * 0.5f;
            float dist = z_b0 - z_a0;
            float pc = sigmoidf_((mid - dv * dist * 0.5f) * s_it);
            float nc = sigmoidf_((mid + dv * dist * 0.5f) * s_it);
            a0 = (pc - nc + 1e-5f) * frcp_(pc + 1e-5f);
        }
        {
            float dv = fminf(fmaxf(fminf(pdv1, dv1), -10.f), 0.f);
            float mid = (s_a1 + s_b1) * 0.5f;
            float dist = z_b1 - z_a1;
            float pc = sigmoidf_((mid - dv * dist * 0.5f) * s_it);
            float nc = sigmoidf_((mid + dv * dist * 0.5f) * s_it);
            a1 = (pc - nc + 1e-5f) * frcp_(pc + 1e-5f);
        }
        if (lane >= nI) a0 = 0.f;
        if (64 + lane >= nI) a1 = 0.f;

        // ---- weights = alpha * excl_cumprod(1-alpha+1e-10); cdf (registers) ----
        float x0 = (lane < nI) ? (1.f - a0 + 1e-10f) : 1.f;
        float x1 = (64 + lane < nI) ? (1.f - a1 + 1e-10f) : 1.f;
        float sc0 = scan_mul64(x0, lane);
        float sc1 = scan_mul64(x1, lane);
        float tot0 = __shfl(sc0, 63, 64);
        float e0 = __shfl_up(sc0, 1, 64); if (lane == 0) e0 = 1.f;
        float e1 = __shfl_up(sc1, 1, 64); if (lane == 0) e1 = 1.f;
        e1 *= tot0;
        float p0 = (lane < nI) ? (a0 * e0 + 1e-5f) : 0.f;
        float p1 = (64 + lane < nI) ? (a1 * e1 + 1e-5f) : 0.f;
        float c0 = scan_add64(p0, lane);
        float c1 = scan_add64(p1, lane);
        float T0 = __shfl(c0, 63, 64);
        float T1 = __shfl(c1, 63, 64);
        float S = T0 + T1;
        float rS = 1.f / S;  // precise: CDF feeds searchsorted
        float cv0 = c0 * rS;           // cdf[1+lane]       (lane < nI)
        float cv1 = (c1 + T0) * rS;    // cdf[65+lane]      (64+lane < nI)

        // ---- inverse-CDF sampling via ballot-count (== searchsorted right) ----
        float val0 = (lane < nI) ? cv0 : 2.f;
        float val1 = (64 + lane < nI) ? cv1 : 2.f;
        int mylo = 0;
#pragma unroll
        for (int j = 0; j < 16; j++) {
            float u = (float)j / 15.f;
            unsigned long long b0 = __ballot(val0 <= u);
            unsigned long long b1 = __ballot(val1 <= u);
            int cnt = 1 + __popcll(b0) + __popcll(b1);
            if (lane == j) mylo = cnt;
        }
        // clamp indices for all lanes (lanes >= 16 produce unused garbage)
        int below = mylo - 1; if (below < 0) below = 0; if (below > M - 1) below = M - 1;
        int above = (mylo < M - 1) ? mylo : (M - 1);
        if (above < 0) above = 0;
        // register cdf gather: cdf[idx] = idx==0 ? 0 : (idx<=64 ? cv0@(idx-1) : cv1@(idx-65))
        float cb_a = __shfl(cv0, (below - 1) & 63, 64);
        float cb_b = __shfl(cv1, (below - 65) & 63, 64);
        float cb = (below == 0) ? 0.f : ((below <= 64) ? cb_a : cb_b);
        float ca_a = __shfl(cv0, (above - 1) & 63, 64);
        float ca_b = __shfl(cv1, (above - 65) & 63, 64);
        float ca = (above == 0) ? 0.f : ((above <= 64) ? ca_a : ca_b);
        float bb = dcur[below], ba = dcur[above];
        float u_l = (float)lane / 15.f;
        float den = ca - cb; if (den < 1e-5f) den = 1.f;
        float tt = (u_l - cb) / den;  // precise: sample positions
        float dd_s = bb + tt * (ba - bb);   // valid for lane < 16 only

        // ---- fine SDF eval: 16 samples, 4 lanes per sample; h1 via shfl ----
        int sIdx = lane >> 2, q = lane & 3;
        float dd = __shfl(dd_s, sIdx, 64);
        float sfv;  // this group's sdf value (all 4 lanes)
        {
            float px = fmaf(dd, dxv, ox), py = fmaf(dd, dyv, oy), pz = fmaf(dd, dzv, oz);
            float h1r[16];
#pragma unroll
            for (int kk = 0; kk < 16; kk++) {
                v4f wk = *(const v4f*)&wl[W1I + 4 * (q * 16 + kk)];
                float a = wk.w;
                a = fmaf(px, wk.x, a);
                a = fmaf(py, wk.y, a);
                a = fmaf(pz, wk.z, a);
                h1r[kk] = softplusf_(a);
            }
            v2f acc[8];
            const v2f* b2s = (const v2f*)&wl[B2 + q * 16];
#pragma unroll
            for (int jj = 0; jj < 8; jj++) acc[jj] = b2s[jj];
#pragma unroll
            for (int k = 0; k < 64; k++) {
                float h = __shfl(h1r[k & 15], (sIdx << 2) + (k >> 4), 64);
                v2f hh = {h, h};
                const v4f* row = (const v4f*)(sw2 + (k << 6) + q * 16);   // global, L1-hot
#pragma unroll
                for (int j4 = 0; j4 < 4; j4++) {
                    v4f r = row[j4];
                    v2f rlo = {r.x, r.y}, rhi = {r.z, r.w};
                    acc[2 * j4] = __builtin_elementwise_fma(hh, rlo, acc[2 * j4]);
                    acc[2 * j4 + 1] = __builtin_elementwise_fma(hh, rhi, acc[2 * j4 + 1]);
                }
            }
            float part = 0.f;
#pragma unroll
            for (int jj = 0; jj < 8; jj++) {
                part = fmaf(softplusf_(acc[jj].x), wl[W3 + q * 16 + 2 * jj], part);
                part = fmaf(softplusf_(acc[jj].y), wl[W3 + q * 16 + 2 * jj + 1], part);
            }
            part += __shfl_xor(part, 1, 64);
            part += __shfl_xor(part, 2, 64);
            float o_ = sb3v + part;
            sfv = sqrtf(px * px + py * py + pz * pz) - 0.8f + 0.1f * o_;
        }

        // ---- stable merge, in-place (all reads precede all writes in-wave) ----
        float df_[16];
#pragma unroll
        for (int j = 0; j < 16; j++) df_[j] = __shfl(dd_s, j, 64);
        float sdf_route = __shfl(sfv, 4 * lane, 64);  // fine sample lane's sdf

        float dval0 = dcur[lane], sval0 = scur[lane];
        bool v1ok = (64 + lane < M);
        float dval1 = v1ok ? dcur[64 + lane] : 3.4e38f;
        float sval1 = v1ok ? scur[64 + lane] : 0.f;

        int cnt0 = 0, cnt1 = 0;
#pragma unroll
        for (int j = 0; j < 16; j++) {
            cnt0 += (df_[j] < dval0) ? 1 : 0;
            cnt1 += (df_[j] < dval1) ? 1 : 0;
        }
        int mypos = 0;
#pragma unroll
        for (int j = 0; j < 16; j++) {
            float vj = df_[j];
            unsigned long long b0 = __ballot(dval0 <= vj);
            unsigned long long b1 = __ballot(dval1 <= vj);
            int cnt = __popcll(b0) + __popcll(b1);
            if (lane == j) mypos = cnt;
        }
        WSYNC();
        dcur[lane + cnt0] = dval0; scur[lane + cnt0] = sval0;
        if (v1ok) { dcur[64 + lane + cnt1] = dval1; scur[64 + lane + cnt1] = sval1; }
        if (lane < 16) {
            dcur[mypos + lane] = dd_s;
            scur[mypos + lane] = sdf_route;
        }
        WSYNC();
        M += 16;
    }

    // ---- final render (M = 128); reuse _sdf; alphas in registers ----
    float ci0 = sigmoidf_(scur[lane] * sfin);
    float ci1 = sigmoidf_(scur[64 + lane] * sfin);
    float tdn = __shfl_down(ci0, 1, 64);
    float tc1 = __shfl(ci1, 0, 64);
    float cn0 = (lane == 63) ? tc1 : tdn;
    float cn1 = __shfl_down(ci1, 1, 64);

    float a0 = fmaxf((ci0 - cn0) * frcp_(ci0 + 1e-10f), 0.f);
    float a1 = (64 + lane < 127) ? fmaxf((ci1 - cn1) * frcp_(ci1 + 1e-10f), 0.f) : 0.f;

    float x0 = 1.f - a0 + 1e-10f;
    float x1 = (64 + lane < 127) ? (1.f - a1 + 1e-10f) : 1.f;
    float sc0 = scan_mul64(x0, lane);
    float sc1 = scan_mul64(x1, lane);
    float tot0 = __shfl(sc0, 63, 64);
    float e0 = __shfl_up(sc0, 1, 64); if (lane == 0) e0 = 1.f;
    float e1 = __shfl_up(sc1, 1, 64); if (lane == 0) e1 = 1.f;
    e1 *= tot0;
    float vw0 = a0 * e0;
    float vw1 = a1 * e1;

    // radiance weights are wave-uniform -> scalar loads from global (sL1-hot)
    float r0 = 0.f, r1 = 0.f, r2 = 0.f;
#pragma unroll 1
    for (int pass = 0; pass < 2; pass++) {
        int i = lane + 64 * pass;
        float vw = pass ? vw1 : vw0;
        if (i < 127) {
            float dm = 0.5f * (dcur[i + 1] + dcur[i]);
            float px = fmaf(dm, dxv, ox), py = fmaf(dm, dyv, oy), pz = fmaf(dm, dzv, oz);
            float g0 = rb2x, g1 = rb2y, g2 = rb2z;
#pragma unroll 4
            for (int j = 0; j < 64; j++) {
                float a = rb1[j];
                a = fmaf(px, rw1[j], a);
                a = fmaf(py, rw1[64 + j], a);
                a = fmaf(pz, rw1[128 + j], a);
                a = fmaf(dxv, rw1[192 + j], a);
                a = fmaf(dyv, rw1[256 + j], a);
                a = fmaf(dzv, rw1[320 + j], a);
                float h = softplusf_(a);
                g0 = fmaf(h, rw2[3 * j], g0);
                g1 = fmaf(h, rw2[3 * j + 1], g1);
                g2 = fmaf(h, rw2[3 * j + 2], g2);
            }
            r0 = fmaf(vw, sigmoidf_(g0), r0);
            r1 = fmaf(vw, sigmoidf_(g1), r1);
            r2 = fmaf(vw, sigmoidf_(g2), r2);
        }
    }
#pragma unroll
    for (int dd = 1; dd < 64; dd <<= 1) {
        r0 += __shfl_xor(r0, dd, 64);
        r1 += __shfl_xor(r1, dd, 64);
        r2 += __shfl_xor(r2, dd, 64);
    }
    if (lane == 0) {
        outp[ray * 3] = r0;
        outp[ray * 3 + 1] = r1;
        outp[ray * 3 + 2] = r2;
    }
}

extern "C" void kernel_launch(void* const* d_in, const int* in_sizes, int n_in,
                              void* d_out, int out_size, void* d_ws, size_t ws_size,
                              hipStream_t stream) {
    const float* rays_o = (const float*)d_in[0];
    const float* rays_d = (const float*)d_in[1];
    const float* nearp  = (const float*)d_in[2];
    const float* farp   = (const float*)d_in[3];
    const float* sptr   = (const float*)d_in[4];
    const float* sw1    = (const float*)d_in[5];
    const float* sb1    = (const float*)d_in[6];
    const float* sw2    = (const float*)d_in[7];
    const float* sb2    = (const float*)d_in[8];
    const float* sw3    = (const float*)d_in[9];
    const float* sb3    = (const float*)d_in[10];
    const float* rw1    = (const float*)d_in[11];
    const float* rb1    = (const float*)d_in[12];
    const float* rw2    = (const float*)d_in[13];
    const float* rb2    = (const float*)d_in[14];
    float* outp = (float*)d_out;

    neus_render_kernel<<<dim3(N_RAYS / 4), dim3(256), 0, stream>>>(
        rays_o, rays_d, nearp, farp, sptr,
        sw1, sb1, sw2, sb2, sw3, sb3,
        rw1, rb1, rw2, rb2, outp);
}

// Round 11
// 421.833 us; speedup vs baseline: 10.7087x; 10.7087x over previous
//
#include <hip/hip_runtime.h>

#define N_RAYS 16384

typedef float v2f __attribute__((ext_vector_type(2)));
typedef float v4f __attribute__((ext_vector_type(4)));

// LDS weight layout (float offsets)
#define W1I   0        // [64][4] : {w1x, w1y, w1z, b1}
#define W2    256      // [64][64] row-major
#define B2    4352     // [64]
#define W3    4416     // [64]
#define WTOT  4480

// wave-local "barrier": compiler ordering only; HW DS pipe is in-order per wave
#define WSYNC() do { __builtin_amdgcn_wave_barrier(); asm volatile("" ::: "memory"); } while (0)

__device__ __forceinline__ float softplusf_(float x) {
    float e = __builtin_amdgcn_exp2f(fabsf(x) * -1.44269504088896340736f);
    float l = __builtin_amdgcn_logf(1.f + e);   // log2(1+e)
    return fmaxf(x, 0.f) + 0.69314718055994530942f * l;
}

__device__ __forceinline__ float sigmoidf_(float x) {
    float e = __builtin_amdgcn_exp2f(-fabsf(x) * 1.44269504088896340736f);
    float r = __builtin_amdgcn_rcpf(1.f + e);
    return x >= 0.f ? r : e * r;
}

__device__ __forceinline__ float frcp_(float x) { return __builtin_amdgcn_rcpf(x); }

__device__ __forceinline__ float scan_mul64(float x, int lane) {
#pragma unroll
    for (int d = 1; d < 64; d <<= 1) {
        float y = __shfl_up(x, d, 64);
        if (lane >= d) x *= y;
    }
    return x;
}

__device__ __forceinline__ float scan_add64(float x, int lane) {
#pragma unroll
    for (int d = 1; d < 64; d <<= 1) {
        float y = __shfl_up(x, d, 64);
        if (lane >= d) x += y;
    }
    return x;
}

// quad-broadcast via DPP (pure VALU, replaces ds_bpermute-based __shfl):
// every lane of a 4-lane quad reads quad element KB.
#define QB(x, KB) __int_as_float(__builtin_amdgcn_mov_dpp( \
    __float_as_int(x), (KB) * 0x55, 0xF, 0xF, false))

__global__ void __launch_bounds__(256) __attribute__((amdgpu_waves_per_eu(4, 4)))
neus_render_kernel(
    const float* __restrict__ rays_o, const float* __restrict__ rays_d,
    const float* __restrict__ nearp, const float* __restrict__ farp,
    const float* __restrict__ sptr,
    const float* __restrict__ sw1, const float* __restrict__ sb1,
    const float* __restrict__ sw2, const float* __restrict__ sb2,
    const float* __restrict__ sw3, const float* __restrict__ sb3,
    const float* __restrict__ rw1, const float* __restrict__ rb1,
    const float* __restrict__ rw2, const float* __restrict__ rb2,
    float* __restrict__ outp) {
    const int tid = threadIdx.x;
    const int wave = tid >> 6;
    const int lane = tid & 63;
    const int ray = blockIdx.x * 4 + wave;

    __shared__ float wl[WTOT];
    __shared__ float dlds[4][132], slds[4][132];

    // ---- ray data loads (issue early) ----
    float ox = rays_o[ray * 3], oy = rays_o[ray * 3 + 1], oz = rays_o[ray * 3 + 2];
    float dxv = rays_d[ray * 3], dyv = rays_d[ray * 3 + 1], dzv = rays_d[ray * 3 + 2];
    const float nearv = nearp[ray], farv = farp[ray];
    const float sb3v = sb3[0];
    const float sfin = sptr[0];
    const float rb2x = rb2[0], rb2y = rb2[1], rb2z = rb2[2];

    // ---- cooperative weight staging (only real block barrier) ----
    if (tid < 64) {
        int i = tid;
        wl[W1I + 4 * i + 0] = sw1[i];
        wl[W1I + 4 * i + 1] = sw1[64 + i];
        wl[W1I + 4 * i + 2] = sw1[128 + i];
        wl[W1I + 4 * i + 3] = sb1[i];
        wl[B2 + i] = sb2[i];
        wl[W3 + i] = sw3[i];
    }
    for (int i = tid; i < 4096; i += 256) wl[W2 + i] = sw2[i];
    __syncthreads();

    float nrm = sqrtf(dxv * dxv + dyv * dyv + dzv * dzv);
    dxv /= nrm; dyv /= nrm; dzv /= nrm;

    float* dcur = &dlds[wave][0];
    float* scur = &slds[wave][0];

    // ---- coarse: 64 samples, one per lane ----
    {
        float t = (float)lane / 63.f;
        float dc = nearv * (1.f - t) + farv * t;
        float px = fmaf(dc, dxv, ox), py = fmaf(dc, dyv, oy), pz = fmaf(dc, dzv, oz);
        v2f acc[32];
        const v2f* b2v = (const v2f*)&wl[B2];
#pragma unroll
        for (int j = 0; j < 32; j++) acc[j] = b2v[j];
#pragma unroll 4
        for (int k = 0; k < 64; k++) {
            v4f wk = *(const v4f*)&wl[W1I + 4 * k];
            float a = wk.w;
            a = fmaf(px, wk.x, a);
            a = fmaf(py, wk.y, a);
            a = fmaf(pz, wk.z, a);
            float h = softplusf_(a);
            v2f hh = {h, h};
            const v4f* row4 = (const v4f*)&wl[W2 + (k << 6)];
#pragma unroll
            for (int j4 = 0; j4 < 16; j4++) {
                v4f r = row4[j4];
                v2f rlo = {r.x, r.y}, rhi = {r.z, r.w};
                acc[2 * j4] = __builtin_elementwise_fma(hh, rlo, acc[2 * j4]);
                acc[2 * j4 + 1] = __builtin_elementwise_fma(hh, rhi, acc[2 * j4 + 1]);
            }
        }
        float out = sb3v;
#pragma unroll
        for (int j = 0; j < 32; j++) {
            out = fmaf(softplusf_(acc[j].x), wl[W3 + 2 * j], out);
            out = fmaf(softplusf_(acc[j].y), wl[W3 + 2 * j + 1], out);
        }
        dcur[lane] = dc;
        scur[lane] = sqrtf(px * px + py * py + pz * pz) - 0.8f + 0.1f * out;
    }
    WSYNC();

    int M = 64;
#pragma unroll 1
    for (int it = 0; it < 4; ++it) {
        const float s_it = 64.f * (float)(1 << it);
        const int nI = M - 1;

        // ---- dot_val + alpha, in registers (i0 = lane, i1 = 64+lane) ----
        float s_a0 = scur[lane], s_b0 = scur[lane + 1];
        float z_a0 = dcur[lane], z_b0 = dcur[lane + 1];
        float s_a1 = scur[64 + lane], s_b1 = scur[64 + lane + 1];
        float z_a1 = dcur[64 + lane], z_b1 = dcur[64 + lane + 1];
        float dv0 = (s_b0 - s_a0) * frcp_(z_b0 - z_a0 + 1e-5f);
        float dv1 = (s_b1 - s_a1) * frcp_(z_b1 - z_a1 + 1e-5f);
        float pdv0 = __shfl_up(dv0, 1, 64); if (lane == 0) pdv0 = 0.f;
        float t_p = __shfl_up(dv1, 1, 64);
        float t_63 = __shfl(dv0, 63, 64);
        float pdv1 = (lane == 0) ? t_63 : t_p;

        float a0, a1;
        {
            float dv = fminf(fmaxf(fminf(pdv0, dv0), -10.f), 0.f);
            float mid = (s_a0 + s_b0) * 0.5f;
            float dist = z_b0 - z_a0;
            float pc = sigmoidf_((mid - dv * dist * 0.5f) * s_it);
            float nc = sigmoidf_((mid + dv * dist * 0.5f) * s_it);
            a0 = (pc - nc + 1e-5f) * frcp_(pc + 1e-5f);
        }
        {
            float dv = fminf(fmaxf(fminf(pdv1, dv1), -10.f), 0.f);
            float mid = (s_a1 + s_b1) * 0.5f;
            float dist = z_b1 - z_a1;
            float pc = sigmoidf_((mid - dv * dist * 0.5f) * s_it);
            float nc = sigmoidf_((mid + dv * dist * 0.5f) * s_it);
            a1 = (pc - nc + 1e-5f) * frcp_(pc + 1e-5f);
        }
        if (lane >= nI) a0 = 0.f;
        if (64 + lane >= nI) a1 = 0.f;

        // ---- weights = alpha * excl_cumprod(1-alpha+1e-10); cdf (registers) ----
        float x0 = (lane < nI) ? (1.f - a0 + 1e-10f) : 1.f;
        float x1 = (64 + lane < nI) ? (1.f - a1 + 1e-10f) : 1.f;
        float sc0 = scan_mul64(x0, lane);
        float sc1 = scan_mul64(x1, lane);
        float tot0 = __shfl(sc0, 63, 64);
        float e0 = __shfl_up(sc0, 1, 64); if (lane == 0) e0 = 1.f;
        float e1 = __shfl_up(sc1, 1, 64); if (lane == 0) e1 = 1.f;
        e1 *= tot0;
        float p0 = (lane < nI) ? (a0 * e0 + 1e-5f) : 0.f;
        float p1 = (64 + lane < nI) ? (a1 * e1 + 1e-5f) : 0.f;
        float c0 = scan_add64(p0, lane);
        float c1 = scan_add64(p1, lane);
        float T0 = __shfl(c0, 63, 64);
        float T1 = __shfl(c1, 63, 64);
        float S = T0 + T1;
        float rS = 1.f / S;  // precise: CDF feeds searchsorted
        float cv0 = c0 * rS;           // cdf[1+lane]       (lane < nI)
        float cv1 = (c1 + T0) * rS;    // cdf[65+lane]      (64+lane < nI)

        // ---- inverse-CDF sampling via ballot-count (== searchsorted right) ----
        float val0 = (lane < nI) ? cv0 : 2.f;
        float val1 = (64 + lane < nI) ? cv1 : 2.f;
        int mylo = 0;
#pragma unroll
        for (int j = 0; j < 16; j++) {
            float u = (float)j / 15.f;
            unsigned long long b0 = __ballot(val0 <= u);
            unsigned long long b1 = __ballot(val1 <= u);
            int cnt = 1 + __popcll(b0) + __popcll(b1);
            if (lane == j) mylo = cnt;
        }
        // clamp indices for all lanes (lanes >= 16 produce unused garbage)
        int below = mylo - 1; if (below < 0) below = 0; if (below > M - 1) below = M - 1;
        int above = (mylo < M - 1) ? mylo : (M - 1);
        if (above < 0) above = 0;
        // register cdf gather: cdf[idx] = idx==0 ? 0 : (idx<=64 ? cv0@(idx-1) : cv1@(idx-65))
        float cb_a = __shfl(cv0, (below - 1) & 63, 64);
        float cb_b = __shfl(cv1, (below - 65) & 63, 64);
        float cb = (below == 0) ? 0.f : ((below <= 64) ? cb_a : cb_b);
        float ca_a = __shfl(cv0, (above - 1) & 63, 64);
        float ca_b = __shfl(cv1, (above - 65) & 63, 64);
        float ca = (above == 0) ? 0.f : ((above <= 64) ? ca_a : ca_b);
        float bb = dcur[below], ba = dcur[above];
        float u_l = (float)lane / 15.f;
        float den = ca - cb; if (den < 1e-5f) den = 1.f;
        float tt = (u_l - cb) / den;  // precise: sample positions
        float dd_s = bb + tt * (ba - bb);   // valid for lane < 16 only

        // ---- fine SDF eval: 16 samples, 4 lanes per sample; h1 via DPP quad-bcast ----
        int sIdx = lane >> 2, q = lane & 3;
        float dd = __shfl(dd_s, sIdx, 64);
        float sfv;  // this group's sdf value (all 4 lanes)
        {
            float px = fmaf(dd, dxv, ox), py = fmaf(dd, dyv, oy), pz = fmaf(dd, dzv, oz);
            float h1r[16];
#pragma unroll
            for (int kk = 0; kk < 16; kk++) {
                v4f wk = *(const v4f*)&wl[W1I + 4 * (q * 16 + kk)];
                float a = wk.w;
                a = fmaf(px, wk.x, a);
                a = fmaf(py, wk.y, a);
                a = fmaf(pz, wk.z, a);
                h1r[kk] = softplusf_(a);
            }
            v2f acc[8];
            const v2f* b2s = (const v2f*)&wl[B2 + q * 16];
#pragma unroll
            for (int jj = 0; jj < 8; jj++) acc[jj] = b2s[jj];
            // k-order: KB*16 + kk, ascending (identical accumulation order).
            // lane (lane&~3)+KB holds h1 for k=KB*16+kk at h1r[kk]; QB routes it.
#define FINE_W2_BLOCK(KB)                                                          \
            _Pragma("unroll")                                                      \
            for (int kk = 0; kk < 16; kk++) {                                      \
                int k = (KB) * 16 + kk;                                            \
                float h = QB(h1r[kk], KB);                                         \
                v2f hh = {h, h};                                                   \
                const v4f* row = (const v4f*)&wl[W2 + (k << 6) + q * 16];          \
                _Pragma("unroll")                                                  \
                for (int j4 = 0; j4 < 4; j4++) {                                   \
                    v4f r = row[j4];                                               \
                    v2f rlo = {r.x, r.y}, rhi = {r.z, r.w};                        \
                    acc[2 * j4] = __builtin_elementwise_fma(hh, rlo, acc[2 * j4]); \
                    acc[2 * j4 + 1] = __builtin_elementwise_fma(hh, rhi, acc[2 * j4 + 1]); \
                }                                                                  \
            }
            FINE_W2_BLOCK(0)
            FINE_W2_BLOCK(1)
            FINE_W2_BLOCK(2)
            FINE_W2_BLOCK(3)
#undef FINE_W2_BLOCK
            float part = 0.f;
#pragma unroll
            for (int jj = 0; jj < 8; jj++) {
                part = fmaf(softplusf_(acc[jj].x), wl[W3 + q * 16 + 2 * jj], part);
                part = fmaf(softplusf_(acc[jj].y), wl[W3 + q * 16 + 2 * jj + 1], part);
            }
            part += __shfl_xor(part, 1, 64);
            part += __shfl_xor(part, 2, 64);
            float o_ = sb3v + part;
            sfv = sqrtf(px * px + py * py + pz * pz) - 0.8f + 0.1f * o_;
        }

        // ---- stable merge, in-place (all reads precede all writes in-wave) ----
        float df_[16];
#pragma unroll
        for (int j = 0; j < 16; j++) df_[j] = __shfl(dd_s, j, 64);
        float sdf_route = __shfl(sfv, 4 * lane, 64);  // fine sample lane's sdf

        float dval0 = dcur[lane], sval0 = scur[lane];
        bool v1ok = (64 + lane < M);
        float dval1 = v1ok ? dcur[64 + lane] : 3.4e38f;
        float sval1 = v1ok ? scur[64 + lane] : 0.f;

        int cnt0 = 0, cnt1 = 0;
#pragma unroll
        for (int j = 0; j < 16; j++) {
            cnt0 += (df_[j] < dval0) ? 1 : 0;
            cnt1 += (df_[j] < dval1) ? 1 : 0;
        }
        int mypos = 0;
#pragma unroll
        for (int j = 0; j < 16; j++) {
            float vj = df_[j];
            unsigned long long b0 = __ballot(dval0 <= vj);
            unsigned long long b1 = __ballot(dval1 <= vj);
            int cnt = __popcll(b0) + __popcll(b1);
            if (lane == j) mypos = cnt;
        }
        WSYNC();
        dcur[lane + cnt0] = dval0; scur[lane + cnt0] = sval0;
        if (v1ok) { dcur[64 + lane + cnt1] = dval1; scur[64 + lane + cnt1] = sval1; }
        if (lane < 16) {
            dcur[mypos + lane] = dd_s;
            scur[mypos + lane] = sdf_route;
        }
        WSYNC();
        M += 16;
    }

    // ---- final render (M = 128); reuse _sdf; alphas in registers ----
    float ci0 = sigmoidf_(scur[lane] * sfin);
    float ci1 = sigmoidf_(scur[64 + lane] * sfin);
    float tdn = __shfl_down(ci0, 1, 64);
    float tc1 = __shfl(ci1, 0, 64);
    float cn0 = (lane == 63) ? tc1 : tdn;
    float cn1 = __shfl_down(ci1, 1, 64);

    float a0 = fmaxf((ci0 - cn0) * frcp_(ci0 + 1e-10f), 0.f);
    float a1 = (64 + lane < 127) ? fmaxf((ci1 - cn1) * frcp_(ci1 + 1e-10f), 0.f) : 0.f;

    float x0 = 1.f - a0 + 1e-10f;
    float x1 = (64 + lane < 127) ? (1.f - a1 + 1e-10f) : 1.f;
    float sc0 = scan_mul64(x0, lane);
    float sc1 = scan_mul64(x1, lane);
    float tot0 = __shfl(sc0, 63, 64);
    float e0 = __shfl_up(sc0, 1, 64); if (lane == 0) e0 = 1.f;
    float e1 = __shfl_up(sc1, 1, 64); if (lane == 0) e1 = 1.f;
    e1 *= tot0;
    float vw0 = a0 * e0;
    float vw1 = a1 * e1;

    // radiance: packed v_pk_fma_f32 layer-1 (weights wave-uniform -> scalar loads)
    v2f vpx2, vpy2, vpz2, vdx2 = {dxv, dxv}, vdy2 = {dyv, dyv}, vdz2 = {dzv, dzv};
    const v2f* rb1v = (const v2f*)rb1;
    const v2f* w0v = (const v2f*)rw1;
    const v2f* w1v = (const v2f*)(rw1 + 64);
    const v2f* w2v = (const v2f*)(rw1 + 128);
    const v2f* w3v = (const v2f*)(rw1 + 192);
    const v2f* w4v = (const v2f*)(rw1 + 256);
    const v2f* w5v = (const v2f*)(rw1 + 320);

    float r0 = 0.f, r1 = 0.f, r2 = 0.f;
#pragma unroll 1
    for (int pass = 0; pass < 2; pass++) {
        int i = lane + 64 * pass;
        float vw = pass ? vw1 : vw0;
        if (i < 127) {
            float dm = 0.5f * (dcur[i + 1] + dcur[i]);
            float px = fmaf(dm, dxv, ox), py = fmaf(dm, dyv, oy), pz = fmaf(dm, dzv, oz);
            vpx2.x = px; vpx2.y = px;
            vpy2.x = py; vpy2.y = py;
            vpz2.x = pz; vpz2.y = pz;
            float g0 = rb2x, g1 = rb2y, g2 = rb2z;
#pragma unroll 4
            for (int jp = 0; jp < 32; jp++) {
                v2f a = rb1v[jp];
                a = __builtin_elementwise_fma(vpx2, w0v[jp], a);
                a = __builtin_elementwise_fma(vpy2, w1v[jp], a);
                a = __builtin_elementwise_fma(vpz2, w2v[jp], a);
                a = __builtin_elementwise_fma(vdx2, w3v[jp], a);
                a = __builtin_elementwise_fma(vdy2, w4v[jp], a);
                a = __builtin_elementwise_fma(vdz2, w5v[jp], a);
                float h0 = softplusf_(a.x);
                float h1 = softplusf_(a.y);
                int j = 2 * jp;
                g0 = fmaf(h0, rw2[3 * j], g0);
                g1 = fmaf(h0, rw2[3 * j + 1], g1);
                g2 = fmaf(h0, rw2[3 * j + 2], g2);
                g0 = fmaf(h1, rw2[3 * j + 3], g0);
                g1 = fmaf(h1, rw2[3 * j + 4], g1);
                g2 = fmaf(h1, rw2[3 * j + 5], g2);
            }
            r0 = fmaf(vw, sigmoidf_(g0), r0);
            r1 = fmaf(vw, sigmoidf_(g1), r1);
            r2 = fmaf(vw, sigmoidf_(g2), r2);
        }
    }
#pragma unroll
    for (int dd = 1; dd < 64; dd <<= 1) {
        r0 += __shfl_xor(r0, dd, 64);
        r1 += __shfl_xor(r1, dd, 64);
        r2 += __shfl_xor(r2, dd, 64);
    }
    if (lane == 0) {
        outp[ray * 3] = r0;
        outp[ray * 3 + 1] = r1;
        outp[ray * 3 + 2] = r2;
    }
}

extern "C" void kernel_launch(void* const* d_in, const int* in_sizes, int n_in,
                              void* d_out, int out_size, void* d_ws, size_t ws_size,
                              hipStream_t stream) {
    const float* rays_o = (const float*)d_in[0];
    const float* rays_d = (const float*)d_in[1];
    const float* nearp  = (const float*)d_in[2];
    const float* farp   = (const float*)d_in[3];
    const float* sptr   = (const float*)d_in[4];
    const float* sw1    = (const float*)d_in[5];
    const float* sb1    = (const float*)d_in[6];
    const float* sw2    = (const float*)d_in[7];
    const float* sb2    = (const float*)d_in[8];
    const float* sw3    = (const float*)d_in[9];
    const float* sb3    = (const float*)d_in[10];
    const float* rw1    = (const float*)d_in[11];
    const float* rb1    = (const float*)d_in[12];
    const float* rw2    = (const float*)d_in[13];
    const float* rb2    = (const float*)d_in[14];
    float* outp = (float*)d_out;

    neus_render_kernel<<<dim3(N_RAYS / 4), dim3(256), 0, stream>>>(
        rays_o, rays_d, nearp, farp, sptr,
        sw1, sb1, sw2, sb2, sw3, sb3,
        rw1, rb1, rw2, rb2, outp);
}

// Round 12
// 413.640 us; speedup vs baseline: 10.9208x; 1.0198x over previous
//
#include <hip/hip_runtime.h>

#define N_RAYS 16384

typedef float v2f __attribute__((ext_vector_type(2)));
typedef float v4f __attribute__((ext_vector_type(4)));

// LDS weight layout (float offsets)
#define W1I   0        // [64][4] : {w1x, w1y, w1z, b1}
#define W2    256      // [64][64] row-major
#define B2    4352     // [64]
#define W3    4416     // [64]
#define WTOT  4480

// wave-local "barrier": compiler ordering only; HW DS pipe is in-order per wave
#define WSYNC() do { __builtin_amdgcn_wave_barrier(); asm volatile("" ::: "memory"); } while (0)

// direct softplus: ln2*log2(1+exp2(x*log2e)); args |x|<88 guaranteed by weight stats
__device__ __forceinline__ float softplusf_(float x) {
    float e = __builtin_amdgcn_exp2f(x * 1.44269504088896340736f);
    float l = __builtin_amdgcn_logf(1.f + e);
    return 0.69314718055994530942f * l;
}

// direct sigmoid: rcp(1+exp2(-x*log2e)); safe for all x (inf->0, 0->1)
__device__ __forceinline__ float sigmoidf_(float x) {
    float e = __builtin_amdgcn_exp2f(-x * 1.44269504088896340736f);
    return __builtin_amdgcn_rcpf(1.f + e);
}

__device__ __forceinline__ float frcp_(float x) { return __builtin_amdgcn_rcpf(x); }

__device__ __forceinline__ float scan_mul64(float x, int lane) {
#pragma unroll
    for (int d = 1; d < 64; d <<= 1) {
        float y = __shfl_up(x, d, 64);
        if (lane >= d) x *= y;
    }
    return x;
}

__device__ __forceinline__ float scan_add64(float x, int lane) {
#pragma unroll
    for (int d = 1; d < 64; d <<= 1) {
        float y = __shfl_up(x, d, 64);
        if (lane >= d) x += y;
    }
    return x;
}

// quad-broadcast via DPP (pure VALU, replaces ds_bpermute-based __shfl):
// every lane of a 4-lane quad reads quad element KB.
#define QB(x, KB) __int_as_float(__builtin_amdgcn_mov_dpp( \
    __float_as_int(x), (KB) * 0x55, 0xF, 0xF, false))

__global__ void __launch_bounds__(256) __attribute__((amdgpu_waves_per_eu(4, 4)))
neus_render_kernel(
    const float* __restrict__ rays_o, const float* __restrict__ rays_d,
    const float* __restrict__ nearp, const float* __restrict__ farp,
    const float* __restrict__ sptr,
    const float* __restrict__ sw1, const float* __restrict__ sb1,
    const float* __restrict__ sw2, const float* __restrict__ sb2,
    const float* __restrict__ sw3, const float* __restrict__ sb3,
    const float* __restrict__ rw1, const float* __restrict__ rb1,
    const float* __restrict__ rw2, const float* __restrict__ rb2,
    float* __restrict__ outp) {
    const int tid = threadIdx.x;
    const int wave = tid >> 6;
    const int lane = tid & 63;
    const int ray = blockIdx.x * 4 + wave;

    __shared__ float wl[WTOT];
    __shared__ float dlds[4][132], slds[4][132];

    // ---- ray data loads (issue early) ----
    float ox = rays_o[ray * 3], oy = rays_o[ray * 3 + 1], oz = rays_o[ray * 3 + 2];
    float dxv = rays_d[ray * 3], dyv = rays_d[ray * 3 + 1], dzv = rays_d[ray * 3 + 2];
    const float nearv = nearp[ray], farv = farp[ray];
    const float sb3v = sb3[0];
    const float sfin = sptr[0];
    const float rb2x = rb2[0], rb2y = rb2[1], rb2z = rb2[2];

    // ---- cooperative weight staging (only real block barrier) ----
    if (tid < 64) {
        int i = tid;
        wl[W1I + 4 * i + 0] = sw1[i];
        wl[W1I + 4 * i + 1] = sw1[64 + i];
        wl[W1I + 4 * i + 2] = sw1[128 + i];
        wl[W1I + 4 * i + 3] = sb1[i];
        wl[B2 + i] = sb2[i];
        wl[W3 + i] = sw3[i];
    }
    for (int i = tid; i < 4096; i += 256) wl[W2 + i] = sw2[i];
    __syncthreads();

    float nrm = sqrtf(dxv * dxv + dyv * dyv + dzv * dzv);
    dxv /= nrm; dyv /= nrm; dzv /= nrm;

    float* dcur = &dlds[wave][0];
    float* scur = &slds[wave][0];

    // ---- coarse: 64 samples, one per lane ----
    {
        float t = (float)lane / 63.f;
        float dc = nearv * (1.f - t) + farv * t;
        float px = fmaf(dc, dxv, ox), py = fmaf(dc, dyv, oy), pz = fmaf(dc, dzv, oz);
        v2f acc[32];
        const v2f* b2v = (const v2f*)&wl[B2];
#pragma unroll
        for (int j = 0; j < 32; j++) acc[j] = b2v[j];
#pragma unroll 4
        for (int k = 0; k < 64; k++) {
            v4f wk = *(const v4f*)&wl[W1I + 4 * k];
            float a = wk.w;
            a = fmaf(px, wk.x, a);
            a = fmaf(py, wk.y, a);
            a = fmaf(pz, wk.z, a);
            float h = softplusf_(a);
            v2f hh = {h, h};
            const v4f* row4 = (const v4f*)&wl[W2 + (k << 6)];
#pragma unroll
            for (int j4 = 0; j4 < 16; j4++) {
                v4f r = row4[j4];
                v2f rlo = {r.x, r.y}, rhi = {r.z, r.w};
                acc[2 * j4] = __builtin_elementwise_fma(hh, rlo, acc[2 * j4]);
                acc[2 * j4 + 1] = __builtin_elementwise_fma(hh, rhi, acc[2 * j4 + 1]);
            }
        }
        float out = sb3v;
#pragma unroll
        for (int j = 0; j < 32; j++) {
            out = fmaf(softplusf_(acc[j].x), wl[W3 + 2 * j], out);
            out = fmaf(softplusf_(acc[j].y), wl[W3 + 2 * j + 1], out);
        }
        dcur[lane] = dc;
        scur[lane] = sqrtf(px * px + py * py + pz * pz) - 0.8f + 0.1f * out;
    }
    WSYNC();

    int M = 64;
#pragma unroll 1
    for (int it = 0; it < 4; ++it) {
        const float s_it = 64.f * (float)(1 << it);
        const int nI = M - 1;

        // ---- dot_val + alpha, in registers (i0 = lane, i1 = 64+lane) ----
        float s_a0 = scur[lane], s_b0 = scur[lane + 1];
        float z_a0 = dcur[lane], z_b0 = dcur[lane + 1];
        float s_a1 = scur[64 + lane], s_b1 = scur[64 + lane + 1];
        float z_a1 = dcur[64 + lane], z_b1 = dcur[64 + lane + 1];
        float dv0 = (s_b0 - s_a0) * frcp_(z_b0 - z_a0 + 1e-5f);
        float dv1 = (s_b1 - s_a1) * frcp_(z_b1 - z_a1 + 1e-5f);
        float pdv0 = __shfl_up(dv0, 1, 64); if (lane == 0) pdv0 = 0.f;
        float t_p = __shfl_up(dv1, 1, 64);
        float t_63 = __shfl(dv0, 63, 64);
        float pdv1 = (lane == 0) ? t_63 : t_p;

        float a0, a1;
        {
            float dv = fminf(fmaxf(fminf(pdv0, dv0), -10.f), 0.f);
            float mid = (s_a0 + s_b0) * 0.5f;
            float dist = z_b0 - z_a0;
            float pc = sigmoidf_((mid - dv * dist * 0.5f) * s_it);
            float nc = sigmoidf_((mid + dv * dist * 0.5f) * s_it);
            a0 = (pc - nc + 1e-5f) * frcp_(pc + 1e-5f);
        }
        {
            float dv = fminf(fmaxf(fminf(pdv1, dv1), -10.f), 0.f);
            float mid = (s_a1 + s_b1) * 0.5f;
            float dist = z_b1 - z_a1;
            float pc = sigmoidf_((mid - dv * dist * 0.5f) * s_it);
            float nc = sigmoidf_((mid + dv * dist * 0.5f) * s_it);
            a1 = (pc - nc + 1e-5f) * frcp_(pc + 1e-5f);
        }
        if (lane >= nI) a0 = 0.f;
        if (64 + lane >= nI) a1 = 0.f;

        // ---- weights = alpha * excl_cumprod(1-alpha+1e-10); cdf (registers) ----
        float x0 = (lane < nI) ? (1.f - a0 + 1e-10f) : 1.f;
        float x1 = (64 + lane < nI) ? (1.f - a1 + 1e-10f) : 1.f;
        float sc0 = scan_mul64(x0, lane);
        float sc1 = scan_mul64(x1, lane);
        float tot0 = __shfl(sc0, 63, 64);
        float e0 = __shfl_up(sc0, 1, 64); if (lane == 0) e0 = 1.f;
        float e1 = __shfl_up(sc1, 1, 64); if (lane == 0) e1 = 1.f;
        e1 *= tot0;
        float p0 = (lane < nI) ? (a0 * e0 + 1e-5f) : 0.f;
        float p1 = (64 + lane < nI) ? (a1 * e1 + 1e-5f) : 0.f;
        float c0 = scan_add64(p0, lane);
        float c1 = scan_add64(p1, lane);
        float T0 = __shfl(c0, 63, 64);
        float T1 = __shfl(c1, 63, 64);
        float S = T0 + T1;
        float rS = 1.f / S;  // precise: CDF feeds searchsorted
        float cv0 = c0 * rS;           // cdf[1+lane]       (lane < nI)
        float cv1 = (c1 + T0) * rS;    // cdf[65+lane]      (64+lane < nI)

        // ---- inverse-CDF sampling via ballot-count (== searchsorted right) ----
        float val0 = (lane < nI) ? cv0 : 2.f;
        float val1 = (64 + lane < nI) ? cv1 : 2.f;
        int mylo = 0;
#pragma unroll
        for (int j = 0; j < 16; j++) {
            float u = (float)j / 15.f;
            unsigned long long b0 = __ballot(val0 <= u);
            unsigned long long b1 = __ballot(val1 <= u);
            int cnt = 1 + __popcll(b0) + __popcll(b1);
            if (lane == j) mylo = cnt;
        }
        // clamp indices for all lanes (lanes >= 16 produce unused garbage)
        int below = mylo - 1; if (below < 0) below = 0; if (below > M - 1) below = M - 1;
        int above = (mylo < M - 1) ? mylo : (M - 1);
        if (above < 0) above = 0;
        // register cdf gather: cdf[idx] = idx==0 ? 0 : (idx<=64 ? cv0@(idx-1) : cv1@(idx-65))
        float cb_a = __shfl(cv0, (below - 1) & 63, 64);
        float cb_b = __shfl(cv1, (below - 65) & 63, 64);
        float cb = (below == 0) ? 0.f : ((below <= 64) ? cb_a : cb_b);
        float ca_a = __shfl(cv0, (above - 1) & 63, 64);
        float ca_b = __shfl(cv1, (above - 65) & 63, 64);
        float ca = (above == 0) ? 0.f : ((above <= 64) ? ca_a : ca_b);
        float bb = dcur[below], ba = dcur[above];
        float u_l = (float)lane / 15.f;
        float den = ca - cb; if (den < 1e-5f) den = 1.f;
        float tt = (u_l - cb) / den;  // precise: sample positions
        float dd_s = bb + tt * (ba - bb);   // valid for lane < 16 only

        // ---- fine SDF eval: 16 samples, 4 lanes per sample; h1 via DPP quad-bcast ----
        int sIdx = lane >> 2, q = lane & 3;
        float dd = __shfl(dd_s, sIdx, 64);
        float sfv;  // this group's sdf value (all 4 lanes)
        {
            float px = fmaf(dd, dxv, ox), py = fmaf(dd, dyv, oy), pz = fmaf(dd, dzv, oz);
            float h1r[16];
#pragma unroll
            for (int kk = 0; kk < 16; kk++) {
                v4f wk = *(const v4f*)&wl[W1I + 4 * (q * 16 + kk)];
                float a = wk.w;
                a = fmaf(px, wk.x, a);
                a = fmaf(py, wk.y, a);
                a = fmaf(pz, wk.z, a);
                h1r[kk] = softplusf_(a);
            }
            v2f acc[8];
            const v2f* b2s = (const v2f*)&wl[B2 + q * 16];
#pragma unroll
            for (int jj = 0; jj < 8; jj++) acc[jj] = b2s[jj];
            // k-order: KB*16 + kk, ascending (identical accumulation order).
            // lane (lane&~3)+KB holds h1 for k=KB*16+kk at h1r[kk]; QB routes it.
#define FINE_W2_BLOCK(KB)                                                          \
            _Pragma("unroll")                                                      \
            for (int kk = 0; kk < 16; kk++) {                                      \
                int k = (KB) * 16 + kk;                                            \
                float h = QB(h1r[kk], KB);                                         \
                v2f hh = {h, h};                                                   \
                const v4f* row = (const v4f*)&wl[W2 + (k << 6) + q * 16];          \
                _Pragma("unroll")                                                  \
                for (int j4 = 0; j4 < 4; j4++) {                                   \
                    v4f r = row[j4];                                               \
                    v2f rlo = {r.x, r.y}, rhi = {r.z, r.w};                        \
                    acc[2 * j4] = __builtin_elementwise_fma(hh, rlo, acc[2 * j4]); \
                    acc[2 * j4 + 1] = __builtin_elementwise_fma(hh, rhi, acc[2 * j4 + 1]); \
                }                                                                  \
            }
            FINE_W2_BLOCK(0)
            FINE_W2_BLOCK(1)
            FINE_W2_BLOCK(2)
            FINE_W2_BLOCK(3)
#undef FINE_W2_BLOCK
            float part = 0.f;
#pragma unroll
            for (int jj = 0; jj < 8; jj++) {
                part = fmaf(softplusf_(acc[jj].x), wl[W3 + q * 16 + 2 * jj], part);
                part = fmaf(softplusf_(acc[jj].y), wl[W3 + q * 16 + 2 * jj + 1], part);
            }
            part += __shfl_xor(part, 1, 64);
            part += __shfl_xor(part, 2, 64);
            float o_ = sb3v + part;
            sfv = sqrtf(px * px + py * py + pz * pz) - 0.8f + 0.1f * o_;
        }

        // ---- stable merge, in-place; fused count/position loop (no df_ array) ----
        float sdf_route = __shfl(sfv, 4 * lane, 64);  // fine sample lane's sdf

        float dval0 = dcur[lane], sval0 = scur[lane];
        bool v1ok = (64 + lane < M);
        float dval1 = v1ok ? dcur[64 + lane] : 3.4e38f;
        float sval1 = v1ok ? scur[64 + lane] : 0.f;

        int cnt0 = 0, cnt1 = 0, mypos = 0;
#pragma unroll
        for (int j = 0; j < 16; j++) {
            float vj = __shfl(dd_s, j, 64);
            cnt0 += (vj < dval0) ? 1 : 0;
            cnt1 += (vj < dval1) ? 1 : 0;
            unsigned long long b0 = __ballot(dval0 <= vj);
            unsigned long long b1 = __ballot(dval1 <= vj);
            int cnt = __popcll(b0) + __popcll(b1);
            if (lane == j) mypos = cnt;
        }
        WSYNC();
        dcur[lane + cnt0] = dval0; scur[lane + cnt0] = sval0;
        if (v1ok) { dcur[64 + lane + cnt1] = dval1; scur[64 + lane + cnt1] = sval1; }
        if (lane < 16) {
            dcur[mypos + lane] = dd_s;
            scur[mypos + lane] = sdf_route;
        }
        WSYNC();
        M += 16;
    }

    // ---- final render (M = 128); reuse _sdf; alphas in registers ----
    float ci0 = sigmoidf_(scur[lane] * sfin);
    float ci1 = sigmoidf_(scur[64 + lane] * sfin);
    float tdn = __shfl_down(ci0, 1, 64);
    float tc1 = __shfl(ci1, 0, 64);
    float cn0 = (lane == 63) ? tc1 : tdn;
    float cn1 = __shfl_down(ci1, 1, 64);

    float a0 = fmaxf((ci0 - cn0) * frcp_(ci0 + 1e-10f), 0.f);
    float a1 = (64 + lane < 127) ? fmaxf((ci1 - cn1) * frcp_(ci1 + 1e-10f), 0.f) : 0.f;

    float x0 = 1.f - a0 + 1e-10f;
    float x1 = (64 + lane < 127) ? (1.f - a1 + 1e-10f) : 1.f;
    float sc0 = scan_mul64(x0, lane);
    float sc1 = scan_mul64(x1, lane);
    float tot0 = __shfl(sc0, 63, 64);
    float e0 = __shfl_up(sc0, 1, 64); if (lane == 0) e0 = 1.f;
    float e1 = __shfl_up(sc1, 1, 64); if (lane == 0) e1 = 1.f;
    e1 *= tot0;
    float vw0 = a0 * e0;
    float vw1 = a1 * e1;

    // radiance: packed v_pk_fma_f32 layer-1 (weights wave-uniform -> scalar loads)
    v2f vpx2, vpy2, vpz2, vdx2 = {dxv, dxv}, vdy2 = {dyv, dyv}, vdz2 = {dzv, dzv};
    const v2f* rb1v = (const v2f*)rb1;
    const v2f* w0v = (const v2f*)rw1;
    const v2f* w1v = (const v2f*)(rw1 + 64);
    const v2f* w2v = (const v2f*)(rw1 + 128);
    const v2f* w3v = (const v2f*)(rw1 + 192);
    const v2f* w4v = (const v2f*)(rw1 + 256);
    const v2f* w5v = (const v2f*)(rw1 + 320);

    float r0 = 0.f, r1 = 0.f, r2 = 0.f;
#pragma unroll 1
    for (int pass = 0; pass < 2; pass++) {
        int i = lane + 64 * pass;
        float vw = pass ? vw1 : vw0;
        if (i < 127) {
            float dm = 0.5f * (dcur[i + 1] + dcur[i]);
            float px = fmaf(dm, dxv, ox), py = fmaf(dm, dyv, oy), pz = fmaf(dm, dzv, oz);
            vpx2.x = px; vpx2.y = px;
            vpy2.x = py; vpy2.y = py;
            vpz2.x = pz; vpz2.y = pz;
            float g0 = rb2x, g1 = rb2y, g2 = rb2z;
#pragma unroll 4
            for (int jp = 0; jp < 32; jp++) {
                v2f a = rb1v[jp];
                a = __builtin_elementwise_fma(vpx2, w0v[jp], a);
                a = __builtin_elementwise_fma(vpy2, w1v[jp], a);
                a = __builtin_elementwise_fma(vpz2, w2v[jp], a);
                a = __builtin_elementwise_fma(vdx2, w3v[jp], a);
                a = __builtin_elementwise_fma(vdy2, w4v[jp], a);
                a = __builtin_elementwise_fma(vdz2, w5v[jp], a);
                float h0 = softplusf_(a.x);
                float h1 = softplusf_(a.y);
                int j = 2 * jp;
                g0 = fmaf(h0, rw2[3 * j], g0);
                g1 = fmaf(h0, rw2[3 * j + 1], g1);
                g2 = fmaf(h0, rw2[3 * j + 2], g2);
                g0 = fmaf(h1, rw2[3 * j + 3], g0);
                g1 = fmaf(h1, rw2[3 * j + 4], g1);
                g2 = fmaf(h1, rw2[3 * j + 5], g2);
            }
            r0 = fmaf(vw, sigmoidf_(g0), r0);
            r1 = fmaf(vw, sigmoidf_(g1), r1);
            r2 = fmaf(vw, sigmoidf_(g2), r2);
        }
    }
#pragma unroll
    for (int dd = 1; dd < 64; dd <<= 1) {
        r0 += __shfl_xor(r0, dd, 64);
        r1 += __shfl_xor(r1, dd, 64);
        r2 += __shfl_xor(r2, dd, 64);
    }
    if (lane == 0) {
        outp[ray * 3] = r0;
        outp[ray * 3 + 1] = r1;
        outp[ray * 3 + 2] = r2;
    }
}

extern "C" void kernel_launch(void* const* d_in, const int* in_sizes, int n_in,
                              void* d_out, int out_size, void* d_ws, size_t ws_size,
                              hipStream_t stream) {
    const float* rays_o = (const float*)d_in[0];
    const float* rays_d = (const float*)d_in[1];
    const float* nearp  = (const float*)d_in[2];
    const float* farp   = (const float*)d_in[3];
    const float* sptr   = (const float*)d_in[4];
    const float* sw1    = (const float*)d_in[5];
    const float* sb1    = (const float*)d_in[6];
    const float* sw2    = (const float*)d_in[7];
    const float* sb2    = (const float*)d_in[8];
    const float* sw3    = (const float*)d_in[9];
    const float* sb3    = (const float*)d_in[10];
    const float* rw1    = (const float*)d_in[11];
    const float* rb1    = (const float*)d_in[12];
    const float* rw2    = (const float*)d_in[13];
    const float* rb2    = (const float*)d_in[14];
    float* outp = (float*)d_out;

    neus_render_kernel<<<dim3(N_RAYS / 4), dim3(256), 0, stream>>>(
        rays_o, rays_d, nearp, farp, sptr,
        sw1, sb1, sw2, sb2, sw3, sb3,
        rw1, rb1, rw2, rb2, outp);
}

// Round 13
// 406.267 us; speedup vs baseline: 11.1190x; 1.0181x over previous
//
#include <hip/hip_runtime.h>

#define N_RAYS 16384

typedef float v2f __attribute__((ext_vector_type(2)));
typedef float v4f __attribute__((ext_vector_type(4)));

// LDS weight layout (float offsets)
#define W1I   0        // [64][4] : {w1x, w1y, w1z, b1}
#define W2    256      // [64][64] row-major
#define B2    4352     // [64]
#define W3    4416     // [64]
#define WTOT  4480

// wave-local "barrier": compiler ordering only; HW DS pipe is in-order per wave
#define WSYNC() do { __builtin_amdgcn_wave_barrier(); asm volatile("" ::: "memory"); } while (0)

// direct softplus: ln2*log2(1+exp2(x*log2e)); args |x|<88 guaranteed by weight stats
__device__ __forceinline__ float softplusf_(float x) {
    float e = __builtin_amdgcn_exp2f(x * 1.44269504088896340736f);
    float l = __builtin_amdgcn_logf(1.f + e);
    return 0.69314718055994530942f * l;
}

// direct sigmoid: rcp(1+exp2(-x*log2e)); safe for all x (inf->0, 0->1)
__device__ __forceinline__ float sigmoidf_(float x) {
    float e = __builtin_amdgcn_exp2f(-x * 1.44269504088896340736f);
    return __builtin_amdgcn_rcpf(1.f + e);
}

__device__ __forceinline__ float frcp_(float x) { return __builtin_amdgcn_rcpf(x); }

// DPP helpers (pure VALU, replace ds_bpermute-based __shfl)
#define UPDPP(oldv, x, ctrl, rmask) __int_as_float(__builtin_amdgcn_update_dpp( \
    __float_as_int(oldv), __float_as_int(x), ctrl, rmask, 0xF, false))
#define SHFL_UP1(x)  UPDPP(0.f, x, 0x138, 0xF)   // wave_shr:1 (lane n <- n-1; lane0 old)
#define SHFL_DN1(x)  UPDPP(0.f, x, 0x130, 0xF)   // wave_shl:1 (lane n <- n+1; lane63 old)

__device__ __forceinline__ float rl_(float x, int l) {
    return __int_as_float(__builtin_amdgcn_readlane(__float_as_int(x), l));
}

// 64-lane inclusive scans via GCN DPP (row scan + cross-row bcast combine)
__device__ __forceinline__ float scan_mul64(float x) {
    x *= UPDPP(1.f, x, 0x111, 0xF);  // row_shr:1
    x *= UPDPP(1.f, x, 0x112, 0xF);  // row_shr:2
    x *= UPDPP(1.f, x, 0x114, 0xF);  // row_shr:4
    x *= UPDPP(1.f, x, 0x118, 0xF);  // row_shr:8
    x *= UPDPP(1.f, x, 0x142, 0xA);  // row_bcast15 -> rows 1,3
    x *= UPDPP(1.f, x, 0x143, 0xC);  // row_bcast31 -> rows 2,3
    return x;
}
__device__ __forceinline__ float scan_add64(float x) {
    x += UPDPP(0.f, x, 0x111, 0xF);
    x += UPDPP(0.f, x, 0x112, 0xF);
    x += UPDPP(0.f, x, 0x114, 0xF);
    x += UPDPP(0.f, x, 0x118, 0xF);
    x += UPDPP(0.f, x, 0x142, 0xA);
    x += UPDPP(0.f, x, 0x143, 0xC);
    return x;
}

// quad-broadcast via DPP: every lane of a 4-lane quad reads quad element KB.
#define QB(x, KB) __int_as_float(__builtin_amdgcn_mov_dpp( \
    __float_as_int(x), (KB) * 0x55, 0xF, 0xF, false))

__global__ void __launch_bounds__(256) __attribute__((amdgpu_waves_per_eu(4, 4)))
neus_render_kernel(
    const float* __restrict__ rays_o, const float* __restrict__ rays_d,
    const float* __restrict__ nearp, const float* __restrict__ farp,
    const float* __restrict__ sptr,
    const float* __restrict__ sw1, const float* __restrict__ sb1,
    const float* __restrict__ sw2, const float* __restrict__ sb2,
    const float* __restrict__ sw3, const float* __restrict__ sb3,
    const float* __restrict__ rw1, const float* __restrict__ rb1,
    const float* __restrict__ rw2, const float* __restrict__ rb2,
    float* __restrict__ outp) {
    const int tid = threadIdx.x;
    const int wave = tid >> 6;
    const int lane = tid & 63;
    const int ray = blockIdx.x * 4 + wave;

    __shared__ float wl[WTOT];
    __shared__ float dlds[4][132], slds[4][132];

    // ---- ray data loads (issue early) ----
    float ox = rays_o[ray * 3], oy = rays_o[ray * 3 + 1], oz = rays_o[ray * 3 + 2];
    float dxv = rays_d[ray * 3], dyv = rays_d[ray * 3 + 1], dzv = rays_d[ray * 3 + 2];
    const float nearv = nearp[ray], farv = farp[ray];
    const float sb3v = sb3[0];
    const float sfin = sptr[0];
    const float rb2x = rb2[0], rb2y = rb2[1], rb2z = rb2[2];

    // ---- cooperative weight staging (only real block barrier) ----
    if (tid < 64) {
        int i = tid;
        wl[W1I + 4 * i + 0] = sw1[i];
        wl[W1I + 4 * i + 1] = sw1[64 + i];
        wl[W1I + 4 * i + 2] = sw1[128 + i];
        wl[W1I + 4 * i + 3] = sb1[i];
        wl[B2 + i] = sb2[i];
        wl[W3 + i] = sw3[i];
    }
    for (int i = tid; i < 4096; i += 256) wl[W2 + i] = sw2[i];
    __syncthreads();

    float nrm = sqrtf(dxv * dxv + dyv * dyv + dzv * dzv);
    dxv /= nrm; dyv /= nrm; dzv /= nrm;

    float* dcur = &dlds[wave][0];
    float* scur = &slds[wave][0];

    // ---- coarse: 64 samples, one per lane ----
    {
        float t = (float)lane / 63.f;
        float dc = nearv * (1.f - t) + farv * t;
        float px = fmaf(dc, dxv, ox), py = fmaf(dc, dyv, oy), pz = fmaf(dc, dzv, oz);
        v2f acc[32];
        const v2f* b2v = (const v2f*)&wl[B2];
#pragma unroll
        for (int j = 0; j < 32; j++) acc[j] = b2v[j];
#pragma unroll 4
        for (int k = 0; k < 64; k++) {
            v4f wk = *(const v4f*)&wl[W1I + 4 * k];
            float a = wk.w;
            a = fmaf(px, wk.x, a);
            a = fmaf(py, wk.y, a);
            a = fmaf(pz, wk.z, a);
            float h = softplusf_(a);
            v2f hh = {h, h};
            const v4f* row4 = (const v4f*)&wl[W2 + (k << 6)];
#pragma unroll
            for (int j4 = 0; j4 < 16; j4++) {
                v4f r = row4[j4];
                v2f rlo = {r.x, r.y}, rhi = {r.z, r.w};
                acc[2 * j4] = __builtin_elementwise_fma(hh, rlo, acc[2 * j4]);
                acc[2 * j4 + 1] = __builtin_elementwise_fma(hh, rhi, acc[2 * j4 + 1]);
            }
        }
        float out = sb3v;
#pragma unroll
        for (int j = 0; j < 32; j++) {
            out = fmaf(softplusf_(acc[j].x), wl[W3 + 2 * j], out);
            out = fmaf(softplusf_(acc[j].y), wl[W3 + 2 * j + 1], out);
        }
        dcur[lane] = dc;
        scur[lane] = sqrtf(px * px + py * py + pz * pz) - 0.8f + 0.1f * out;
    }
    WSYNC();

    int M = 64;
#pragma unroll 1
    for (int it = 0; it < 4; ++it) {
        const float s_it = 64.f * (float)(1 << it);
        const int nI = M - 1;

        // ---- dot_val + alpha, in registers (i0 = lane, i1 = 64+lane) ----
        float s_a0 = scur[lane], s_b0 = scur[lane + 1];
        float z_a0 = dcur[lane], z_b0 = dcur[lane + 1];
        float s_a1 = scur[64 + lane], s_b1 = scur[64 + lane + 1];
        float z_a1 = dcur[64 + lane], z_b1 = dcur[64 + lane + 1];
        float dv0 = (s_b0 - s_a0) * frcp_(z_b0 - z_a0 + 1e-5f);
        float dv1 = (s_b1 - s_a1) * frcp_(z_b1 - z_a1 + 1e-5f);
        float pdv0 = SHFL_UP1(dv0); if (lane == 0) pdv0 = 0.f;
        float t_p = SHFL_UP1(dv1);
        float t_63 = rl_(dv0, 63);
        float pdv1 = (lane == 0) ? t_63 : t_p;

        float a0, a1;
        {
            float dv = fminf(fmaxf(fminf(pdv0, dv0), -10.f), 0.f);
            float mid = (s_a0 + s_b0) * 0.5f;
            float dist = z_b0 - z_a0;
            float pc = sigmoidf_((mid - dv * dist * 0.5f) * s_it);
            float nc = sigmoidf_((mid + dv * dist * 0.5f) * s_it);
            a0 = (pc - nc + 1e-5f) * frcp_(pc + 1e-5f);
        }
        {
            float dv = fminf(fmaxf(fminf(pdv1, dv1), -10.f), 0.f);
            float mid = (s_a1 + s_b1) * 0.5f;
            float dist = z_b1 - z_a1;
            float pc = sigmoidf_((mid - dv * dist * 0.5f) * s_it);
            float nc = sigmoidf_((mid + dv * dist * 0.5f) * s_it);
            a1 = (pc - nc + 1e-5f) * frcp_(pc + 1e-5f);
        }
        if (lane >= nI) a0 = 0.f;
        if (64 + lane >= nI) a1 = 0.f;

        // ---- weights = alpha * excl_cumprod(1-alpha+1e-10); cdf (registers) ----
        float x0 = (lane < nI) ? (1.f - a0 + 1e-10f) : 1.f;
        float x1 = (64 + lane < nI) ? (1.f - a1 + 1e-10f) : 1.f;
        float sc0 = scan_mul64(x0);
        float sc1 = scan_mul64(x1);
        float tot0 = rl_(sc0, 63);
        float e0 = SHFL_UP1(sc0); if (lane == 0) e0 = 1.f;
        float e1 = SHFL_UP1(sc1); if (lane == 0) e1 = 1.f;
        e1 *= tot0;
        float p0 = (lane < nI) ? (a0 * e0 + 1e-5f) : 0.f;
        float p1 = (64 + lane < nI) ? (a1 * e1 + 1e-5f) : 0.f;
        float c0 = scan_add64(p0);
        float c1 = scan_add64(p1);
        float T0 = rl_(c0, 63);
        float T1 = rl_(c1, 63);
        float S = T0 + T1;
        float rS = 1.f / S;  // precise: CDF feeds searchsorted
        float cv0 = c0 * rS;           // cdf[1+lane]       (lane < nI)
        float cv1 = (c1 + T0) * rS;    // cdf[65+lane]      (64+lane < nI)

        // ---- inverse-CDF sampling via ballot-count (== searchsorted right) ----
        float val0 = (lane < nI) ? cv0 : 2.f;
        float val1 = (64 + lane < nI) ? cv1 : 2.f;
        int mylo = 0;
#pragma unroll
        for (int j = 0; j < 16; j++) {
            float u = (float)j / 15.f;
            unsigned long long b0 = __ballot(val0 <= u);
            unsigned long long b1 = __ballot(val1 <= u);
            int cnt = 1 + __popcll(b0) + __popcll(b1);
            if (lane == j) mylo = cnt;
        }
        // clamp indices for all lanes (lanes >= 16 produce unused garbage)
        int below = mylo - 1; if (below < 0) below = 0; if (below > M - 1) below = M - 1;
        int above = (mylo < M - 1) ? mylo : (M - 1);
        if (above < 0) above = 0;
        // register cdf gather: cdf[idx] = idx==0 ? 0 : (idx<=64 ? cv0@(idx-1) : cv1@(idx-65))
        float cb_a = __shfl(cv0, (below - 1) & 63, 64);
        float cb_b = __shfl(cv1, (below - 65) & 63, 64);
        float cb = (below == 0) ? 0.f : ((below <= 64) ? cb_a : cb_b);
        float ca_a = __shfl(cv0, (above - 1) & 63, 64);
        float ca_b = __shfl(cv1, (above - 65) & 63, 64);
        float ca = (above == 0) ? 0.f : ((above <= 64) ? ca_a : ca_b);
        float bb = dcur[below], ba = dcur[above];
        float u_l = (float)lane / 15.f;
        float den = ca - cb; if (den < 1e-5f) den = 1.f;
        float tt = (u_l - cb) / den;  // precise: sample positions
        float dd_s = bb + tt * (ba - bb);   // valid for lane < 16 only

        // ---- fine SDF eval: 16 samples, 4 lanes per sample; h1 via DPP quad-bcast ----
        int sIdx = lane >> 2, q = lane & 3;
        float dd = __shfl(dd_s, sIdx, 64);
        float sfv;  // this group's sdf value (all 4 lanes)
        {
            float px = fmaf(dd, dxv, ox), py = fmaf(dd, dyv, oy), pz = fmaf(dd, dzv, oz);
            float h1r[16];
#pragma unroll
            for (int kk = 0; kk < 16; kk++) {
                v4f wk = *(const v4f*)&wl[W1I + 4 * (q * 16 + kk)];
                float a = wk.w;
                a = fmaf(px, wk.x, a);
                a = fmaf(py, wk.y, a);
                a = fmaf(pz, wk.z, a);
                h1r[kk] = softplusf_(a);
            }
            v2f acc[8];
            const v2f* b2s = (const v2f*)&wl[B2 + q * 16];
#pragma unroll
            for (int jj = 0; jj < 8; jj++) acc[jj] = b2s[jj];
            // k-order: KB*16 + kk, ascending (identical accumulation order).
#define FINE_W2_BLOCK(KB)                                                          \
            _Pragma("unroll")                                                      \
            for (int kk = 0; kk < 16; kk++) {                                      \
                int k = (KB) * 16 + kk;                                            \
                float h = QB(h1r[kk], KB);                                         \
                v2f hh = {h, h};                                                   \
                const v4f* row = (const v4f*)&wl[W2 + (k << 6) + q * 16];          \
                _Pragma("unroll")                                                  \
                for (int j4 = 0; j4 < 4; j4++) {                                   \
                    v4f r = row[j4];                                               \
                    v2f rlo = {r.x, r.y}, rhi = {r.z, r.w};                        \
                    acc[2 * j4] = __builtin_elementwise_fma(hh, rlo, acc[2 * j4]); \
                    acc[2 * j4 + 1] = __builtin_elementwise_fma(hh, rhi, acc[2 * j4 + 1]); \
                }                                                                  \
            }
            FINE_W2_BLOCK(0)
            FINE_W2_BLOCK(1)
            FINE_W2_BLOCK(2)
            FINE_W2_BLOCK(3)
#undef FINE_W2_BLOCK
            float part = 0.f;
#pragma unroll
            for (int jj = 0; jj < 8; jj++) {
                part = fmaf(softplusf_(acc[jj].x), wl[W3 + q * 16 + 2 * jj], part);
                part = fmaf(softplusf_(acc[jj].y), wl[W3 + q * 16 + 2 * jj + 1], part);
            }
            part += __shfl_xor(part, 1, 64);
            part += __shfl_xor(part, 2, 64);
            float o_ = sb3v + part;
            sfv = sqrtf(px * px + py * py + pz * pz) - 0.8f + 0.1f * o_;
        }

        // ---- stable merge, in-place; fused loop, readlane broadcasts ----
        float sdf_route = __shfl(sfv, 4 * lane, 64);  // fine sample lane's sdf

        float dval0 = dcur[lane], sval0 = scur[lane];
        bool v1ok = (64 + lane < M);
        float dval1 = v1ok ? dcur[64 + lane] : 3.4e38f;
        float sval1 = v1ok ? scur[64 + lane] : 0.f;

        int cnt0 = 0, cnt1 = 0, mypos = 0;
#pragma unroll
        for (int j = 0; j < 16; j++) {
            float vj = rl_(dd_s, j);
            cnt0 += (vj < dval0) ? 1 : 0;
            cnt1 += (vj < dval1) ? 1 : 0;
            unsigned long long b0 = __ballot(dval0 <= vj);
            unsigned long long b1 = __ballot(dval1 <= vj);
            int cnt = __popcll(b0) + __popcll(b1);
            if (lane == j) mypos = cnt;
        }
        WSYNC();
        dcur[lane + cnt0] = dval0; scur[lane + cnt0] = sval0;
        if (v1ok) { dcur[64 + lane + cnt1] = dval1; scur[64 + lane + cnt1] = sval1; }
        if (lane < 16) {
            dcur[mypos + lane] = dd_s;
            scur[mypos + lane] = sdf_route;
        }
        WSYNC();
        M += 16;
    }

    // ---- final render (M = 128); reuse _sdf; alphas in registers ----
    float ci0 = sigmoidf_(scur[lane] * sfin);
    float ci1 = sigmoidf_(scur[64 + lane] * sfin);
    float tdn = SHFL_DN1(ci0);
    float tc1 = rl_(ci1, 0);
    float cn0 = (lane == 63) ? tc1 : tdn;
    float cn1 = SHFL_DN1(ci1);  // lane63 garbage; unused (64+63 >= 127)

    float a0 = fmaxf((ci0 - cn0) * frcp_(ci0 + 1e-10f), 0.f);
    float a1 = (64 + lane < 127) ? fmaxf((ci1 - cn1) * frcp_(ci1 + 1e-10f), 0.f) : 0.f;

    float x0 = 1.f - a0 + 1e-10f;
    float x1 = (64 + lane < 127) ? (1.f - a1 + 1e-10f) : 1.f;
    float sc0 = scan_mul64(x0);
    float sc1 = scan_mul64(x1);
    float tot0 = rl_(sc0, 63);
    float e0 = SHFL_UP1(sc0); if (lane == 0) e0 = 1.f;
    float e1 = SHFL_UP1(sc1); if (lane == 0) e1 = 1.f;
    e1 *= tot0;
    float vw0 = a0 * e0;
    float vw1 = a1 * e1;

    // radiance: packed v_pk_fma_f32 layer-1 (weights wave-uniform -> scalar loads)
    v2f vpx2, vpy2, vpz2, vdx2 = {dxv, dxv}, vdy2 = {dyv, dyv}, vdz2 = {dzv, dzv};
    const v2f* rb1v = (const v2f*)rb1;
    const v2f* w0v = (const v2f*)rw1;
    const v2f* w1v = (const v2f*)(rw1 + 64);
    const v2f* w2v = (const v2f*)(rw1 + 128);
    const v2f* w3v = (const v2f*)(rw1 + 192);
    const v2f* w4v = (const v2f*)(rw1 + 256);
    const v2f* w5v = (const v2f*)(rw1 + 320);

    float r0 = 0.f, r1 = 0.f, r2 = 0.f;
#pragma unroll 1
    for (int pass = 0; pass < 2; pass++) {
        int i = lane + 64 * pass;
        float vw = pass ? vw1 : vw0;
        if (i < 127) {
            float dm = 0.5f * (dcur[i + 1] + dcur[i]);
            float px = fmaf(dm, dxv, ox), py = fmaf(dm, dyv, oy), pz = fmaf(dm, dzv, oz);
            vpx2.x = px; vpx2.y = px;
            vpy2.x = py; vpy2.y = py;
            vpz2.x = pz; vpz2.y = pz;
            float g0 = rb2x, g1 = rb2y, g2 = rb2z;
#pragma unroll 4
            for (int jp = 0; jp < 32; jp++) {
                v2f a = rb1v[jp];
                a = __builtin_elementwise_fma(vpx2, w0v[jp], a);
                a = __builtin_elementwise_fma(vpy2, w1v[jp], a);
                a = __builtin_elementwise_fma(vpz2, w2v[jp], a);
                a = __builtin_elementwise_fma(vdx2, w3v[jp], a);
                a = __builtin_elementwise_fma(vdy2, w4v[jp], a);
                a = __builtin_elementwise_fma(vdz2, w5v[jp], a);
                float h0 = softplusf_(a.x);
                float h1 = softplusf_(a.y);
                int j = 2 * jp;
                g0 = fmaf(h0, rw2[3 * j], g0);
                g1 = fmaf(h0, rw2[3 * j + 1], g1);
                g2 = fmaf(h0, rw2[3 * j + 2], g2);
                g0 = fmaf(h1, rw2[3 * j + 3], g0);
                g1 = fmaf(h1, rw2[3 * j + 4], g1);
                g2 = fmaf(h1, rw2[3 * j + 5], g2);
            }
            r0 = fmaf(vw, sigmoidf_(g0), r0);
            r1 = fmaf(vw, sigmoidf_(g1), r1);
            r2 = fmaf(vw, sigmoidf_(g2), r2);
        }
    }
#pragma unroll
    for (int dd = 1; dd < 64; dd <<= 1) {
        r0 += __shfl_xor(r0, dd, 64);
        r1 += __shfl_xor(r1, dd, 64);
        r2 += __shfl_xor(r2, dd, 64);
    }
    if (lane == 0) {
        outp[ray * 3] = r0;
        outp[ray * 3 + 1] = r1;
        outp[ray * 3 + 2] = r2;
    }
}

extern "C" void kernel_launch(void* const* d_in, const int* in_sizes, int n_in,
                              void* d_out, int out_size, void* d_ws, size_t ws_size,
                              hipStream_t stream) {
    const float* rays_o = (const float*)d_in[0];
    const float* rays_d = (const float*)d_in[1];
    const float* nearp  = (const float*)d_in[2];
    const float* farp   = (const float*)d_in[3];
    const float* sptr   = (const float*)d_in[4];
    const float* sw1    = (const float*)d_in[5];
    const float* sb1    = (const float*)d_in[6];
    const float* sw2    = (const float*)d_in[7];
    const float* sb2    = (const float*)d_in[8];
    const float* sw3    = (const float*)d_in[9];
    const float* sb3    = (const float*)d_in[10];
    const float* rw1    = (const float*)d_in[11];
    const float* rb1    = (const float*)d_in[12];
    const float* rw2    = (const float*)d_in[13];
    const float* rb2    = (const float*)d_in[14];
    float* outp = (float*)d_out;

    neus_render_kernel<<<dim3(N_RAYS / 4), dim3(256), 0, stream>>>(
        rays_o, rays_d, nearp, farp, sptr,
        sw1, sb1, sw2, sb2, sw3, sb3,
        rw1, rb1, rw2, rb2, outp);
}

// Round 14
// 324.978 us; speedup vs baseline: 13.9002x; 1.2501x over previous
//
#include <hip/hip_runtime.h>

#define N_RAYS 16384

typedef float v2f __attribute__((ext_vector_type(2)));
typedef float v4f __attribute__((ext_vector_type(4)));

// LDS weight layout (float offsets) — used by the FINE phase only
#define W1I   0        // [64][4] : {w1x, w1y, w1z, b1}
#define W2    256      // [64][64] row-major
#define B2    4352     // [64]
#define W3    4416     // [64]
#define WTOT  4480

#define WSYNC() do { __builtin_amdgcn_wave_barrier(); asm volatile("" ::: "memory"); } while (0)

// direct softplus: ln2*log2(1+exp2(x*log2e)); args bounded well inside fp32 range
__device__ __forceinline__ float softplusf_(float x) {
    float e = __builtin_amdgcn_exp2f(x * 1.44269504088896340736f);
    float l = __builtin_amdgcn_logf(1.f + e);
    return 0.69314718055994530942f * l;
}

// direct sigmoid: rcp(1+exp2(-x*log2e)); safe for all x
__device__ __forceinline__ float sigmoidf_(float x) {
    float e = __builtin_amdgcn_exp2f(-x * 1.44269504088896340736f);
    return __builtin_amdgcn_rcpf(1.f + e);
}

__device__ __forceinline__ float frcp_(float x) { return __builtin_amdgcn_rcpf(x); }

// DPP helpers (pure VALU)
#define UPDPP(oldv, x, ctrl, rmask) __int_as_float(__builtin_amdgcn_update_dpp( \
    __float_as_int(oldv), __float_as_int(x), ctrl, rmask, 0xF, false))
#define SHFL_UP1(x)  UPDPP(0.f, x, 0x138, 0xF)   // wave_shr:1
#define SHFL_DN1(x)  UPDPP(0.f, x, 0x130, 0xF)   // wave_shl:1

__device__ __forceinline__ float rl_(float x, int l) {
    return __int_as_float(__builtin_amdgcn_readlane(__float_as_int(x), l));
}

// 64-lane inclusive scans via GCN DPP
__device__ __forceinline__ float scan_mul64(float x) {
    x *= UPDPP(1.f, x, 0x111, 0xF);
    x *= UPDPP(1.f, x, 0x112, 0xF);
    x *= UPDPP(1.f, x, 0x114, 0xF);
    x *= UPDPP(1.f, x, 0x118, 0xF);
    x *= UPDPP(1.f, x, 0x142, 0xA);
    x *= UPDPP(1.f, x, 0x143, 0xC);
    return x;
}
__device__ __forceinline__ float scan_add64(float x) {
    x += UPDPP(0.f, x, 0x111, 0xF);
    x += UPDPP(0.f, x, 0x112, 0xF);
    x += UPDPP(0.f, x, 0x114, 0xF);
    x += UPDPP(0.f, x, 0x118, 0xF);
    x += UPDPP(0.f, x, 0x142, 0xA);
    x += UPDPP(0.f, x, 0x143, 0xC);
    return x;
}

// quad-broadcast via DPP
#define QB(x, KB) __int_as_float(__builtin_amdgcn_mov_dpp( \
    __float_as_int(x), (KB) * 0x55, 0xF, 0xF, false))

__global__ void __launch_bounds__(256) __attribute__((amdgpu_waves_per_eu(4, 4)))
neus_render_kernel(
    const float* __restrict__ rays_o, const float* __restrict__ rays_d,
    const float* __restrict__ nearp, const float* __restrict__ farp,
    const float* __restrict__ sptr,
    const float* __restrict__ sw1, const float* __restrict__ sb1,
    const float* __restrict__ sw2, const float* __restrict__ sb2,
    const float* __restrict__ sw3, const float* __restrict__ sb3,
    const float* __restrict__ rw1, const float* __restrict__ rb1,
    const float* __restrict__ rw2, const float* __restrict__ rb2,
    float* __restrict__ outp) {
    const int tid = threadIdx.x;
    const int wave = tid >> 6;
    const int lane = tid & 63;
    const int ray = blockIdx.x * 4 + wave;

    __shared__ float wl[WTOT];
    __shared__ float dlds[4][132], slds[4][132];

    // ---- ray data loads (issue early) ----
    float ox = rays_o[ray * 3], oy = rays_o[ray * 3 + 1], oz = rays_o[ray * 3 + 2];
    float dxv = rays_d[ray * 3], dyv = rays_d[ray * 3 + 1], dzv = rays_d[ray * 3 + 2];
    const float nearv = nearp[ray], farv = farp[ray];
    const float sb3v = sb3[0];
    const float sfin = sptr[0];
    const float rb2x = rb2[0], rb2y = rb2[1], rb2z = rb2[2];

    // ---- weight staging for FINE phase (only real block barrier) ----
    if (tid < 64) {
        int i = tid;
        wl[W1I + 4 * i + 0] = sw1[i];
        wl[W1I + 4 * i + 1] = sw1[64 + i];
        wl[W1I + 4 * i + 2] = sw1[128 + i];
        wl[W1I + 4 * i + 3] = sb1[i];
        wl[B2 + i] = sb2[i];
        wl[W3 + i] = sw3[i];
    }
    for (int i = tid; i < 4096; i += 256) wl[W2 + i] = sw2[i];
    __syncthreads();

    float nrm = sqrtf(dxv * dxv + dyv * dyv + dzv * dzv);
    dxv /= nrm; dyv /= nrm; dzv /= nrm;

    float* dcur = &dlds[wave][0];
    float* scur = &slds[wave][0];

    // ---- coarse: 64 samples, one per lane; weights via WAVE-UNIFORM GLOBAL
    //      reads -> scalar s_load pipe (zero DS-pipe traffic) ----
    {
        float t = (float)lane / 63.f;
        float dc = nearv * (1.f - t) + farv * t;
        float px = fmaf(dc, dxv, ox), py = fmaf(dc, dyv, oy), pz = fmaf(dc, dzv, oz);
        v2f acc[32];
        const v2f* b2v = (const v2f*)sb2;   // uniform global
#pragma unroll
        for (int j = 0; j < 32; j++) acc[j] = b2v[j];
#pragma unroll 4
        for (int k = 0; k < 64; k++) {
            float a = sb1[k];               // uniform global (scalar)
            a = fmaf(px, sw1[k], a);
            a = fmaf(py, sw1[64 + k], a);
            a = fmaf(pz, sw1[128 + k], a);
            float h = softplusf_(a);
            v2f hh = {h, h};
            const v2f* row = (const v2f*)(sw2 + (k << 6));   // uniform global row
#pragma unroll
            for (int j = 0; j < 32; j++) acc[j] = __builtin_elementwise_fma(hh, row[j], acc[j]);
        }
        float out = sb3v;
#pragma unroll
        for (int j = 0; j < 32; j++) {
            out = fmaf(softplusf_(acc[j].x), sw3[2 * j], out);
            out = fmaf(softplusf_(acc[j].y), sw3[2 * j + 1], out);
        }
        dcur[lane] = dc;
        scur[lane] = sqrtf(px * px + py * py + pz * pz) - 0.8f + 0.1f * out;
    }
    WSYNC();

    int M = 64;
#pragma unroll 1
    for (int it = 0; it < 4; ++it) {
        const float s_it = 64.f * (float)(1 << it);
        const int nI = M - 1;

        // ---- dot_val + alpha, in registers ----
        float s_a0 = scur[lane], s_b0 = scur[lane + 1];
        float z_a0 = dcur[lane], z_b0 = dcur[lane + 1];
        float s_a1 = scur[64 + lane], s_b1 = scur[64 + lane + 1];
        float z_a1 = dcur[64 + lane], z_b1 = dcur[64 + lane + 1];
        float dv0 = (s_b0 - s_a0) * frcp_(z_b0 - z_a0 + 1e-5f);
        float dv1 = (s_b1 - s_a1) * frcp_(z_b1 - z_a1 + 1e-5f);
        float pdv0 = SHFL_UP1(dv0); if (lane == 0) pdv0 = 0.f;
        float t_p = SHFL_UP1(dv1);
        float t_63 = rl_(dv0, 63);
        float pdv1 = (lane == 0) ? t_63 : t_p;

        float a0, a1;
        {
            float dv = fminf(fmaxf(fminf(pdv0, dv0), -10.f), 0.f);
            float mid = (s_a0 + s_b0) * 0.5f;
            float dist = z_b0 - z_a0;
            float pc = sigmoidf_((mid - dv * dist * 0.5f) * s_it);
            float nc = sigmoidf_((mid + dv * dist * 0.5f) * s_it);
            a0 = (pc - nc + 1e-5f) * frcp_(pc + 1e-5f);
        }
        {
            float dv = fminf(fmaxf(fminf(pdv1, dv1), -10.f), 0.f);
            float mid = (s_a1 + s_b1) * 0.5f;
            float dist = z_b1 - z_a1;
            float pc = sigmoidf_((mid - dv * dist * 0.5f) * s_it);
            float nc = sigmoidf_((mid + dv * dist * 0.5f) * s_it);
            a1 = (pc - nc + 1e-5f) * frcp_(pc + 1e-5f);
        }
        if (lane >= nI) a0 = 0.f;
        if (64 + lane >= nI) a1 = 0.f;

        // ---- weights + cdf (registers, DPP scans) ----
        float x0 = (lane < nI) ? (1.f - a0 + 1e-10f) : 1.f;
        float x1 = (64 + lane < nI) ? (1.f - a1 + 1e-10f) : 1.f;
        float sc0 = scan_mul64(x0);
        float sc1 = scan_mul64(x1);
        float tot0 = rl_(sc0, 63);
        float e0 = SHFL_UP1(sc0); if (lane == 0) e0 = 1.f;
        float e1 = SHFL_UP1(sc1); if (lane == 0) e1 = 1.f;
        e1 *= tot0;
        float p0 = (lane < nI) ? (a0 * e0 + 1e-5f) : 0.f;
        float p1 = (64 + lane < nI) ? (a1 * e1 + 1e-5f) : 0.f;
        float c0 = scan_add64(p0);
        float c1 = scan_add64(p1);
        float T0 = rl_(c0, 63);
        float T1 = rl_(c1, 63);
        float S = T0 + T1;
        float rS = 1.f / S;  // precise: CDF feeds searchsorted
        float cv0 = c0 * rS;
        float cv1 = (c1 + T0) * rS;

        // ---- inverse-CDF sampling via ballot-count ----
        float val0 = (lane < nI) ? cv0 : 2.f;
        float val1 = (64 + lane < nI) ? cv1 : 2.f;
        int mylo = 0;
#pragma unroll
        for (int j = 0; j < 16; j++) {
            float u = (float)j / 15.f;
            unsigned long long b0 = __ballot(val0 <= u);
            unsigned long long b1 = __ballot(val1 <= u);
            int cnt = 1 + __popcll(b0) + __popcll(b1);
            if (lane == j) mylo = cnt;
        }
        int below = mylo - 1; if (below < 0) below = 0; if (below > M - 1) below = M - 1;
        int above = (mylo < M - 1) ? mylo : (M - 1);
        if (above < 0) above = 0;
        float cb_a = __shfl(cv0, (below - 1) & 63, 64);
        float cb_b = __shfl(cv1, (below - 65) & 63, 64);
        float cb = (below == 0) ? 0.f : ((below <= 64) ? cb_a : cb_b);
        float ca_a = __shfl(cv0, (above - 1) & 63, 64);
        float ca_b = __shfl(cv1, (above - 65) & 63, 64);
        float ca = (above == 0) ? 0.f : ((above <= 64) ? ca_a : ca_b);
        float bb = dcur[below], ba = dcur[above];
        float u_l = (float)lane / 15.f;
        float den = ca - cb; if (den < 1e-5f) den = 1.f;
        float tt = (u_l - cb) / den;  // precise: sample positions
        float dd_s = bb + tt * (ba - bb);   // valid for lane < 16 only

        // ---- fine SDF eval: 16 samples, 4 lanes per sample; W2 from LDS ----
        int sIdx = lane >> 2, q = lane & 3;
        float dd = __shfl(dd_s, sIdx, 64);
        float sfv;
        {
            float px = fmaf(dd, dxv, ox), py = fmaf(dd, dyv, oy), pz = fmaf(dd, dzv, oz);
            float h1r[16];
#pragma unroll
            for (int kk = 0; kk < 16; kk++) {
                v4f wk = *(const v4f*)&wl[W1I + 4 * (q * 16 + kk)];
                float a = wk.w;
                a = fmaf(px, wk.x, a);
                a = fmaf(py, wk.y, a);
                a = fmaf(pz, wk.z, a);
                h1r[kk] = softplusf_(a);
            }
            v2f acc[8];
            const v2f* b2s = (const v2f*)&wl[B2 + q * 16];
#pragma unroll
            for (int jj = 0; jj < 8; jj++) acc[jj] = b2s[jj];
#define FINE_W2_BLOCK(KB)                                                          \
            _Pragma("unroll")                                                      \
            for (int kk = 0; kk < 16; kk++) {                                      \
                int k = (KB) * 16 + kk;                                            \
                float h = QB(h1r[kk], KB);                                         \
                v2f hh = {h, h};                                                   \
                const v4f* row = (const v4f*)&wl[W2 + (k << 6) + q * 16];          \
                _Pragma("unroll")                                                  \
                for (int j4 = 0; j4 < 4; j4++) {                                   \
                    v4f r = row[j4];                                               \
                    v2f rlo = {r.x, r.y}, rhi = {r.z, r.w};                        \
                    acc[2 * j4] = __builtin_elementwise_fma(hh, rlo, acc[2 * j4]); \
                    acc[2 * j4 + 1] = __builtin_elementwise_fma(hh, rhi, acc[2 * j4 + 1]); \
                }                                                                  \
            }
            FINE_W2_BLOCK(0)
            FINE_W2_BLOCK(1)
            FINE_W2_BLOCK(2)
            FINE_W2_BLOCK(3)
#undef FINE_W2_BLOCK
            float part = 0.f;
#pragma unroll
            for (int jj = 0; jj < 8; jj++) {
                part = fmaf(softplusf_(acc[jj].x), wl[W3 + q * 16 + 2 * jj], part);
                part = fmaf(softplusf_(acc[jj].y), wl[W3 + q * 16 + 2 * jj + 1], part);
            }
            part += __shfl_xor(part, 1, 64);
            part += __shfl_xor(part, 2, 64);
            float o_ = sb3v + part;
            sfv = sqrtf(px * px + py * py + pz * pz) - 0.8f + 0.1f * o_;
        }

        // ---- stable merge, in-place; fused loop, readlane broadcasts ----
        float sdf_route = __shfl(sfv, 4 * lane, 64);

        float dval0 = dcur[lane], sval0 = scur[lane];
        bool v1ok = (64 + lane < M);
        float dval1 = v1ok ? dcur[64 + lane] : 3.4e38f;
        float sval1 = v1ok ? scur[64 + lane] : 0.f;

        int cnt0 = 0, cnt1 = 0, mypos = 0;
#pragma unroll
        for (int j = 0; j < 16; j++) {
            float vj = rl_(dd_s, j);
            cnt0 += (vj < dval0) ? 1 : 0;
            cnt1 += (vj < dval1) ? 1 : 0;
            unsigned long long b0 = __ballot(dval0 <= vj);
            unsigned long long b1 = __ballot(dval1 <= vj);
            int cnt = __popcll(b0) + __popcll(b1);
            if (lane == j) mypos = cnt;
        }
        WSYNC();
        dcur[lane + cnt0] = dval0; scur[lane + cnt0] = sval0;
        if (v1ok) { dcur[64 + lane + cnt1] = dval1; scur[64 + lane + cnt1] = sval1; }
        if (lane < 16) {
            dcur[mypos + lane] = dd_s;
            scur[mypos + lane] = sdf_route;
        }
        WSYNC();
        M += 16;
    }

    // ---- final render (M = 128); reuse _sdf; alphas in registers ----
    float ci0 = sigmoidf_(scur[lane] * sfin);
    float ci1 = sigmoidf_(scur[64 + lane] * sfin);
    float tdn = SHFL_DN1(ci0);
    float tc1 = rl_(ci1, 0);
    float cn0 = (lane == 63) ? tc1 : tdn;
    float cn1 = SHFL_DN1(ci1);

    float a0 = fmaxf((ci0 - cn0) * frcp_(ci0 + 1e-10f), 0.f);
    float a1 = (64 + lane < 127) ? fmaxf((ci1 - cn1) * frcp_(ci1 + 1e-10f), 0.f) : 0.f;

    float x0 = 1.f - a0 + 1e-10f;
    float x1 = (64 + lane < 127) ? (1.f - a1 + 1e-10f) : 1.f;
    float sc0 = scan_mul64(x0);
    float sc1 = scan_mul64(x1);
    float tot0 = rl_(sc0, 63);
    float e0 = SHFL_UP1(sc0); if (lane == 0) e0 = 1.f;
    float e1 = SHFL_UP1(sc1); if (lane == 0) e1 = 1.f;
    e1 *= tot0;
    float vw0 = a0 * e0;
    float vw1 = a1 * e1;

    // radiance: packed v_pk_fma_f32 layer-1 (weights wave-uniform -> scalar loads)
    v2f vpx2, vpy2, vpz2, vdx2 = {dxv, dxv}, vdy2 = {dyv, dyv}, vdz2 = {dzv, dzv};
    const v2f* rb1v = (const v2f*)rb1;
    const v2f* w0v = (const v2f*)rw1;
    const v2f* w1v = (const v2f*)(rw1 + 64);
    const v2f* w2v = (const v2f*)(rw1 + 128);
    const v2f* w3v = (const v2f*)(rw1 + 192);
    const v2f* w4v = (const v2f*)(rw1 + 256);
    const v2f* w5v = (const v2f*)(rw1 + 320);

    float r0 = 0.f, r1 = 0.f, r2 = 0.f;
#pragma unroll 1
    for (int pass = 0; pass < 2; pass++) {
        int i = lane + 64 * pass;
        float vw = pass ? vw1 : vw0;
        if (i < 127) {
            float dm = 0.5f * (dcur[i + 1] + dcur[i]);
            float px = fmaf(dm, dxv, ox), py = fmaf(dm, dyv, oy), pz = fmaf(dm, dzv, oz);
            vpx2.x = px; vpx2.y = px;
            vpy2.x = py; vpy2.y = py;
            vpz2.x = pz; vpz2.y = pz;
            float g0 = rb2x, g1 = rb2y, g2 = rb2z;
#pragma unroll 4
            for (int jp = 0; jp < 32; jp++) {
                v2f a = rb1v[jp];
                a = __builtin_elementwise_fma(vpx2, w0v[jp], a);
                a = __builtin_elementwise_fma(vpy2, w1v[jp], a);
                a = __builtin_elementwise_fma(vpz2, w2v[jp], a);
                a = __builtin_elementwise_fma(vdx2, w3v[jp], a);
                a = __builtin_elementwise_fma(vdy2, w4v[jp], a);
                a = __builtin_elementwise_fma(vdz2, w5v[jp], a);
                float h0 = softplusf_(a.x);
                float h1 = softplusf_(a.y);
                int j = 2 * jp;
                g0 = fmaf(h0, rw2[3 * j], g0);
                g1 = fmaf(h0, rw2[3 * j + 1], g1);
                g2 = fmaf(h0, rw2[3 * j + 2], g2);
                g0 = fmaf(h1, rw2[3 * j + 3], g0);
                g1 = fmaf(h1, rw2[3 * j + 4], g1);
                g2 = fmaf(h1, rw2[3 * j + 5], g2);
            }
            r0 = fmaf(vw, sigmoidf_(g0), r0);
            r1 = fmaf(vw, sigmoidf_(g1), r1);
            r2 = fmaf(vw, sigmoidf_(g2), r2);
        }
    }
#pragma unroll
    for (int dd = 1; dd < 64; dd <<= 1) {
        r0 += __shfl_xor(r0, dd, 64);
        r1 += __shfl_xor(r1, dd, 64);
        r2 += __shfl_xor(r2, dd, 64);
    }
    if (lane == 0) {
        outp[ray * 3] = r0;
        outp[ray * 3 + 1] = r1;
        outp[ray * 3 + 2] = r2;
    }
}

extern "C" void kernel_launch(void* const* d_in, const int* in_sizes, int n_in,
                              void* d_out, int out_size, void* d_ws, size_t ws_size,
                              hipStream_t stream) {
    const float* rays_o = (const float*)d_in[0];
    const float* rays_d = (const float*)d_in[1];
    const float* nearp  = (const float*)d_in[2];
    const float* farp   = (const float*)d_in[3];
    const float* sptr   = (const float*)d_in[4];
    const float* sw1    = (const float*)d_in[5];
    const float* sb1    = (const float*)d_in[6];
    const float* sw2    = (const float*)d_in[7];
    const float* sb2    = (const float*)d_in[8];
    const float* sw3    = (const float*)d_in[9];
    const float* sb3    = (const float*)d_in[10];
    const float* rw1    = (const float*)d_in[11];
    const float* rb1    = (const float*)d_in[12];
    const float* rw2    = (const float*)d_in[13];
    const float* rb2    = (const float*)d_in[14];
    float* outp = (float*)d_out;

    neus_render_kernel<<<dim3(N_RAYS / 4), dim3(256), 0, stream>>>(
        rays_o, rays_d, nearp, farp, sptr,
        sw1, sb1, sw2, sb2, sw3, sb3,
        rw1, rb1, rw2, rb2, outp);
}

// Round 15
// 307.959 us; speedup vs baseline: 14.6684x; 1.0553x over previous
//
#include <hip/hip_runtime.h>

#define N_RAYS 16384

typedef float v2f __attribute__((ext_vector_type(2)));
typedef float v4f __attribute__((ext_vector_type(4)));

// LDS weight layout (float offsets) — used by the FINE phase only
#define W1I   0        // [64][4] : {w1x, w1y, w1z, b1}
#define W2    256      // [64][64] row-major
#define B2    4352     // [64]
#define W3    4416     // [64]
#define WTOT  4480

#define WSYNC() do { __builtin_amdgcn_wave_barrier(); asm volatile("" ::: "memory"); } while (0)

// direct softplus: ln2*log2(1+exp2(x*log2e)); args bounded well inside fp32 range
__device__ __forceinline__ float softplusf_(float x) {
    float e = __builtin_amdgcn_exp2f(x * 1.44269504088896340736f);
    float l = __builtin_amdgcn_logf(1.f + e);
    return 0.69314718055994530942f * l;
}

// direct sigmoid: rcp(1+exp2(-x*log2e)); safe for all x
__device__ __forceinline__ float sigmoidf_(float x) {
    float e = __builtin_amdgcn_exp2f(-x * 1.44269504088896340736f);
    return __builtin_amdgcn_rcpf(1.f + e);
}

__device__ __forceinline__ float frcp_(float x) { return __builtin_amdgcn_rcpf(x); }

// DPP helpers (pure VALU)
#define UPDPP(oldv, x, ctrl, rmask) __int_as_float(__builtin_amdgcn_update_dpp( \
    __float_as_int(oldv), __float_as_int(x), ctrl, rmask, 0xF, false))
#define SHFL_UP1(x)  UPDPP(0.f, x, 0x138, 0xF)   // wave_shr:1
#define SHFL_DN1(x)  UPDPP(0.f, x, 0x130, 0xF)   // wave_shl:1

__device__ __forceinline__ float rl_(float x, int l) {
    return __int_as_float(__builtin_amdgcn_readlane(__float_as_int(x), l));
}

// 64-lane inclusive scans via GCN DPP
__device__ __forceinline__ float scan_mul64(float x) {
    x *= UPDPP(1.f, x, 0x111, 0xF);
    x *= UPDPP(1.f, x, 0x112, 0xF);
    x *= UPDPP(1.f, x, 0x114, 0xF);
    x *= UPDPP(1.f, x, 0x118, 0xF);
    x *= UPDPP(1.f, x, 0x142, 0xA);
    x *= UPDPP(1.f, x, 0x143, 0xC);
    return x;
}
__device__ __forceinline__ float scan_add64(float x) {
    x += UPDPP(0.f, x, 0x111, 0xF);
    x += UPDPP(0.f, x, 0x112, 0xF);
    x += UPDPP(0.f, x, 0x114, 0xF);
    x += UPDPP(0.f, x, 0x118, 0xF);
    x += UPDPP(0.f, x, 0x142, 0xA);
    x += UPDPP(0.f, x, 0x143, 0xC);
    return x;
}

// quad-broadcast via DPP
#define QB(x, KB) __int_as_float(__builtin_amdgcn_mov_dpp( \
    __float_as_int(x), (KB) * 0x55, 0xF, 0xF, false))

__global__ void __launch_bounds__(256) __attribute__((amdgpu_waves_per_eu(3, 4)))
neus_render_kernel(
    const float* __restrict__ rays_o, const float* __restrict__ rays_d,
    const float* __restrict__ nearp, const float* __restrict__ farp,
    const float* __restrict__ sptr,
    const float* __restrict__ sw1, const float* __restrict__ sb1,
    const float* __restrict__ sw2, const float* __restrict__ sb2,
    const float* __restrict__ sw3, const float* __restrict__ sb3,
    const float* __restrict__ rw1, const float* __restrict__ rb1,
    const float* __restrict__ rw2, const float* __restrict__ rb2,
    float* __restrict__ outp) {
    const int tid = threadIdx.x;
    const int wave = tid >> 6;
    const int lane = tid & 63;
    const int ray = blockIdx.x * 4 + wave;

    __shared__ float wl[WTOT];
    __shared__ float dlds[4][132], slds[4][132];

    // ---- ray data loads (issue early) ----
    float ox = rays_o[ray * 3], oy = rays_o[ray * 3 + 1], oz = rays_o[ray * 3 + 2];
    float dxv = rays_d[ray * 3], dyv = rays_d[ray * 3 + 1], dzv = rays_d[ray * 3 + 2];
    const float nearv = nearp[ray], farv = farp[ray];
    const float sb3v = sb3[0];
    const float sfin = sptr[0];
    const float rb2x = rb2[0], rb2y = rb2[1], rb2z = rb2[2];

    // ---- weight staging for FINE phase (only real block barrier) ----
    if (tid < 64) {
        int i = tid;
        wl[W1I + 4 * i + 0] = sw1[i];
        wl[W1I + 4 * i + 1] = sw1[64 + i];
        wl[W1I + 4 * i + 2] = sw1[128 + i];
        wl[W1I + 4 * i + 3] = sb1[i];
        wl[B2 + i] = sb2[i];
        wl[W3 + i] = sw3[i];
    }
    for (int i = tid; i < 4096; i += 256) wl[W2 + i] = sw2[i];
    __syncthreads();

    float nrm = sqrtf(dxv * dxv + dyv * dyv + dzv * dzv);
    dxv /= nrm; dyv /= nrm; dzv /= nrm;

    float* dcur = &dlds[wave][0];
    float* scur = &slds[wave][0];

    // ---- coarse: 64 samples, one per lane; weights via WAVE-UNIFORM GLOBAL
    //      reads -> scalar s_load pipe (zero DS-pipe traffic) ----
    {
        float t = (float)lane / 63.f;
        float dc = nearv * (1.f - t) + farv * t;
        float px = fmaf(dc, dxv, ox), py = fmaf(dc, dyv, oy), pz = fmaf(dc, dzv, oz);
        v2f acc[32];
        const v2f* b2v = (const v2f*)sb2;   // uniform global
#pragma unroll
        for (int j = 0; j < 32; j++) acc[j] = b2v[j];
#pragma unroll 4
        for (int k = 0; k < 64; k++) {
            float a = sb1[k];               // uniform global (scalar)
            a = fmaf(px, sw1[k], a);
            a = fmaf(py, sw1[64 + k], a);
            a = fmaf(pz, sw1[128 + k], a);
            float h = softplusf_(a);
            v2f hh = {h, h};
            const v2f* row = (const v2f*)(sw2 + (k << 6));   // uniform global row
#pragma unroll
            for (int j = 0; j < 32; j++) acc[j] = __builtin_elementwise_fma(hh, row[j], acc[j]);
        }
        float out = sb3v;
#pragma unroll
        for (int j = 0; j < 32; j++) {
            out = fmaf(softplusf_(acc[j].x), sw3[2 * j], out);
            out = fmaf(softplusf_(acc[j].y), sw3[2 * j + 1], out);
        }
        dcur[lane] = dc;
        scur[lane] = sqrtf(px * px + py * py + pz * pz) - 0.8f + 0.1f * out;
    }
    WSYNC();

    int M = 64;
#pragma unroll 1
    for (int it = 0; it < 4; ++it) {
        const float s_it = 64.f * (float)(1 << it);
        const int nI = M - 1;

        // ---- dot_val + alpha, in registers ----
        float s_a0 = scur[lane], s_b0 = scur[lane + 1];
        float z_a0 = dcur[lane], z_b0 = dcur[lane + 1];
        float s_a1 = scur[64 + lane], s_b1 = scur[64 + lane + 1];
        float z_a1 = dcur[64 + lane], z_b1 = dcur[64 + lane + 1];
        float dv0 = (s_b0 - s_a0) * frcp_(z_b0 - z_a0 + 1e-5f);
        float dv1 = (s_b1 - s_a1) * frcp_(z_b1 - z_a1 + 1e-5f);
        float pdv0 = SHFL_UP1(dv0); if (lane == 0) pdv0 = 0.f;
        float t_p = SHFL_UP1(dv1);
        float t_63 = rl_(dv0, 63);
        float pdv1 = (lane == 0) ? t_63 : t_p;

        float a0, a1;
        {
            float dv = fminf(fmaxf(fminf(pdv0, dv0), -10.f), 0.f);
            float mid = (s_a0 + s_b0) * 0.5f;
            float dist = z_b0 - z_a0;
            float pc = sigmoidf_((mid - dv * dist * 0.5f) * s_it);
            float nc = sigmoidf_((mid + dv * dist * 0.5f) * s_it);
            a0 = (pc - nc + 1e-5f) * frcp_(pc + 1e-5f);
        }
        {
            float dv = fminf(fmaxf(fminf(pdv1, dv1), -10.f), 0.f);
            float mid = (s_a1 + s_b1) * 0.5f;
            float dist = z_b1 - z_a1;
            float pc = sigmoidf_((mid - dv * dist * 0.5f) * s_it);
            float nc = sigmoidf_((mid + dv * dist * 0.5f) * s_it);
            a1 = (pc - nc + 1e-5f) * frcp_(pc + 1e-5f);
        }
        if (lane >= nI) a0 = 0.f;
        if (64 + lane >= nI) a1 = 0.f;

        // ---- weights + cdf (registers, DPP scans) ----
        float x0 = (lane < nI) ? (1.f - a0 + 1e-10f) : 1.f;
        float x1 = (64 + lane < nI) ? (1.f - a1 + 1e-10f) : 1.f;
        float sc0 = scan_mul64(x0);
        float sc1 = scan_mul64(x1);
        float tot0 = rl_(sc0, 63);
        float e0 = SHFL_UP1(sc0); if (lane == 0) e0 = 1.f;
        float e1 = SHFL_UP1(sc1); if (lane == 0) e1 = 1.f;
        e1 *= tot0;
        float p0 = (lane < nI) ? (a0 * e0 + 1e-5f) : 0.f;
        float p1 = (64 + lane < nI) ? (a1 * e1 + 1e-5f) : 0.f;
        float c0 = scan_add64(p0);
        float c1 = scan_add64(p1);
        float T0 = rl_(c0, 63);
        float T1 = rl_(c1, 63);
        float S = T0 + T1;
        float rS = 1.f / S;  // precise: CDF feeds searchsorted
        float cv0 = c0 * rS;
        float cv1 = (c1 + T0) * rS;

        // ---- inverse-CDF sampling via ballot-count ----
        float val0 = (lane < nI) ? cv0 : 2.f;
        float val1 = (64 + lane < nI) ? cv1 : 2.f;
        int mylo = 0;
#pragma unroll
        for (int j = 0; j < 16; j++) {
            float u = (float)j / 15.f;
            unsigned long long b0 = __ballot(val0 <= u);
            unsigned long long b1 = __ballot(val1 <= u);
            int cnt = 1 + __popcll(b0) + __popcll(b1);
            if (lane == j) mylo = cnt;
        }
        int below = mylo - 1; if (below < 0) below = 0; if (below > M - 1) below = M - 1;
        int above = (mylo < M - 1) ? mylo : (M - 1);
        if (above < 0) above = 0;
        float cb_a = __shfl(cv0, (below - 1) & 63, 64);
        float cb_b = __shfl(cv1, (below - 65) & 63, 64);
        float cb = (below == 0) ? 0.f : ((below <= 64) ? cb_a : cb_b);
        float ca_a = __shfl(cv0, (above - 1) & 63, 64);
        float ca_b = __shfl(cv1, (above - 65) & 63, 64);
        float ca = (above == 0) ? 0.f : ((above <= 64) ? ca_a : ca_b);
        float bb = dcur[below], ba = dcur[above];
        float u_l = (float)lane / 15.f;
        float den = ca - cb; if (den < 1e-5f) den = 1.f;
        float tt = (u_l - cb) / den;  // precise: sample positions
        float dd_s = bb + tt * (ba - bb);   // valid for lane < 16 only

        // ---- fine SDF eval: 16 samples, 4 lanes per sample; W2 from LDS ----
        int sIdx = lane >> 2, q = lane & 3;
        float dd = __shfl(dd_s, sIdx, 64);
        float sfv;
        {
            float px = fmaf(dd, dxv, ox), py = fmaf(dd, dyv, oy), pz = fmaf(dd, dzv, oz);
            float h1r[16];
#pragma unroll
            for (int kk = 0; kk < 16; kk++) {
                v4f wk = *(const v4f*)&wl[W1I + 4 * (q * 16 + kk)];
                float a = wk.w;
                a = fmaf(px, wk.x, a);
                a = fmaf(py, wk.y, a);
                a = fmaf(pz, wk.z, a);
                h1r[kk] = softplusf_(a);
            }
            v2f acc[8];
            const v2f* b2s = (const v2f*)&wl[B2 + q * 16];
#pragma unroll
            for (int jj = 0; jj < 8; jj++) acc[jj] = b2s[jj];
#define FINE_W2_BLOCK(KB)                                                          \
            _Pragma("unroll")                                                      \
            for (int kk = 0; kk < 16; kk++) {                                      \
                int k = (KB) * 16 + kk;                                            \
                float h = QB(h1r[kk], KB);                                         \
                v2f hh = {h, h};                                                   \
                const v4f* row = (const v4f*)&wl[W2 + (k << 6) + q * 16];          \
                _Pragma("unroll")                                                  \
                for (int j4 = 0; j4 < 4; j4++) {                                   \
                    v4f r = row[j4];                                               \
                    v2f rlo = {r.x, r.y}, rhi = {r.z, r.w};                        \
                    acc[2 * j4] = __builtin_elementwise_fma(hh, rlo, acc[2 * j4]); \
                    acc[2 * j4 + 1] = __builtin_elementwise_fma(hh, rhi, acc[2 * j4 + 1]); \
                }                                                                  \
            }
            FINE_W2_BLOCK(0)
            FINE_W2_BLOCK(1)
            FINE_W2_BLOCK(2)
            FINE_W2_BLOCK(3)
#undef FINE_W2_BLOCK
            float part = 0.f;
#pragma unroll
            for (int jj = 0; jj < 8; jj++) {
                part = fmaf(softplusf_(acc[jj].x), wl[W3 + q * 16 + 2 * jj], part);
                part = fmaf(softplusf_(acc[jj].y), wl[W3 + q * 16 + 2 * jj + 1], part);
            }
            part += __shfl_xor(part, 1, 64);
            part += __shfl_xor(part, 2, 64);
            float o_ = sb3v + part;
            sfv = sqrtf(px * px + py * py + pz * pz) - 0.8f + 0.1f * o_;
        }

        // ---- stable merge, in-place; fused loop, readlane broadcasts ----
        float sdf_route = __shfl(sfv, 4 * lane, 64);

        float dval0 = dcur[lane], sval0 = scur[lane];
        bool v1ok = (64 + lane < M);
        float dval1 = v1ok ? dcur[64 + lane] : 3.4e38f;
        float sval1 = v1ok ? scur[64 + lane] : 0.f;

        int cnt0 = 0, cnt1 = 0, mypos = 0;
#pragma unroll
        for (int j = 0; j < 16; j++) {
            float vj = rl_(dd_s, j);
            cnt0 += (vj < dval0) ? 1 : 0;
            cnt1 += (vj < dval1) ? 1 : 0;
            unsigned long long b0 = __ballot(dval0 <= vj);
            unsigned long long b1 = __ballot(dval1 <= vj);
            int cnt = __popcll(b0) + __popcll(b1);
            if (lane == j) mypos = cnt;
        }
        WSYNC();
        dcur[lane + cnt0] = dval0; scur[lane + cnt0] = sval0;
        if (v1ok) { dcur[64 + lane + cnt1] = dval1; scur[64 + lane + cnt1] = sval1; }
        if (lane < 16) {
            dcur[mypos + lane] = dd_s;
            scur[mypos + lane] = sdf_route;
        }
        WSYNC();
        M += 16;
    }

    // ---- final render (M = 128); reuse _sdf; alphas in registers ----
    float ci0 = sigmoidf_(scur[lane] * sfin);
    float ci1 = sigmoidf_(scur[64 + lane] * sfin);
    float tdn = SHFL_DN1(ci0);
    float tc1 = rl_(ci1, 0);
    float cn0 = (lane == 63) ? tc1 : tdn;
    float cn1 = SHFL_DN1(ci1);

    float a0 = fmaxf((ci0 - cn0) * frcp_(ci0 + 1e-10f), 0.f);
    float a1 = (64 + lane < 127) ? fmaxf((ci1 - cn1) * frcp_(ci1 + 1e-10f), 0.f) : 0.f;

    float x0 = 1.f - a0 + 1e-10f;
    float x1 = (64 + lane < 127) ? (1.f - a1 + 1e-10f) : 1.f;
    float sc0 = scan_mul64(x0);
    float sc1 = scan_mul64(x1);
    float tot0 = rl_(sc0, 63);
    float e0 = SHFL_UP1(sc0); if (lane == 0) e0 = 1.f;
    float e1 = SHFL_UP1(sc1); if (lane == 0) e1 = 1.f;
    e1 *= tot0;
    float vw0 = a0 * e0;
    float vw1 = a1 * e1;

    // radiance: packed v_pk_fma_f32 layer-1 (weights wave-uniform -> scalar loads)
    v2f vpx2, vpy2, vpz2, vdx2 = {dxv, dxv}, vdy2 = {dyv, dyv}, vdz2 = {dzv, dzv};
    const v2f* rb1v = (const v2f*)rb1;
    const v2f* w0v = (const v2f*)rw1;
    const v2f* w1v = (const v2f*)(rw1 + 64);
    const v2f* w2v = (const v2f*)(rw1 + 128);
    const v2f* w3v = (const v2f*)(rw1 + 192);
    const v2f* w4v = (const v2f*)(rw1 + 256);
    const v2f* w5v = (const v2f*)(rw1 + 320);

    float r0 = 0.f, r1 = 0.f, r2 = 0.f;
#pragma unroll 1
    for (int pass = 0; pass < 2; pass++) {
        int i = lane + 64 * pass;
        float vw = pass ? vw1 : vw0;
        if (i < 127) {
            float dm = 0.5f * (dcur[i + 1] + dcur[i]);
            float px = fmaf(dm, dxv, ox), py = fmaf(dm, dyv, oy), pz = fmaf(dm, dzv, oz);
            vpx2.x = px; vpx2.y = px;
            vpy2.x = py; vpy2.y = py;
            vpz2.x = pz; vpz2.y = pz;
            float g0 = rb2x, g1 = rb2y, g2 = rb2z;
#pragma unroll 4
            for (int jp = 0; jp < 32; jp++) {
                v2f a = rb1v[jp];
                a = __builtin_elementwise_fma(vpx2, w0v[jp], a);
                a = __builtin_elementwise_fma(vpy2, w1v[jp], a);
                a = __builtin_elementwise_fma(vpz2, w2v[jp], a);
                a = __builtin_elementwise_fma(vdx2, w3v[jp], a);
                a = __builtin_elementwise_fma(vdy2, w4v[jp], a);
                a = __builtin_elementwise_fma(vdz2, w5v[jp], a);
                float h0 = softplusf_(a.x);
                float h1 = softplusf_(a.y);
                int j = 2 * jp;
                g0 = fmaf(h0, rw2[3 * j], g0);
                g1 = fmaf(h0, rw2[3 * j + 1], g1);
                g2 = fmaf(h0, rw2[3 * j + 2], g2);
                g0 = fmaf(h1, rw2[3 * j + 3], g0);
                g1 = fmaf(h1, rw2[3 * j + 4], g1);
                g2 = fmaf(h1, rw2[3 * j + 5], g2);
            }
            r0 = fmaf(vw, sigmoidf_(g0), r0);
            r1 = fmaf(vw, sigmoidf_(g1), r1);
            r2 = fmaf(vw, sigmoidf_(g2), r2);
        }
    }
#pragma unroll
    for (int dd = 1; dd < 64; dd <<= 1) {
        r0 += __shfl_xor(r0, dd, 64);
        r1 += __shfl_xor(r1, dd, 64);
        r2 += __shfl_xor(r2, dd, 64);
    }
    if (lane == 0) {
        outp[ray * 3] = r0;
        outp[ray * 3 + 1] = r1;
        outp[ray * 3 + 2] = r2;
    }
}

extern "C" void kernel_launch(void* const* d_in, const int* in_sizes, int n_in,
                              void* d_out, int out_size, void* d_ws, size_t ws_size,
                              hipStream_t stream) {
    const float* rays_o = (const float*)d_in[0];
    const float* rays_d = (const float*)d_in[1];
    const float* nearp  = (const float*)d_in[2];
    const float* farp   = (const float*)d_in[3];
    const float* sptr   = (const float*)d_in[4];
    const float* sw1    = (const float*)d_in[5];
    const float* sb1    = (const float*)d_in[6];
    const float* sw2    = (const float*)d_in[7];
    const float* sb2    = (const float*)d_in[8];
    const float* sw3    = (const float*)d_in[9];
    const float* sb3    = (const float*)d_in[10];
    const float* rw1    = (const float*)d_in[11];
    const float* rb1    = (const float*)d_in[12];
    const float* rw2    = (const float*)d_in[13];
    const float* rb2    = (const float*)d_in[14];
    float* outp = (float*)d_out;

    neus_render_kernel<<<dim3(N_RAYS / 4), dim3(256), 0, stream>>>(
        rays_o, rays_d, nearp, farp, sptr,
        sw1, sb1, sw2, sb2, sw3, sb3,
        rw1, rb1, rw2, rb2, outp);
}